// Round 4
// baseline (8169.881 us; speedup 1.0000x reference)
//
#include <hip/hip_runtime.h>
#include <hip/hip_bf16.h>

#define NN 100000
#define NE 1600000
#define NCHUNK 391   // ceil(100000/256)

typedef unsigned short u16;
typedef unsigned int   u32;

__device__ __forceinline__ float bfu(u32 v){ union{u32 i; float f;} w; w.i = v<<16; return w.f; }
__device__ __forceinline__ float bf_lo(u32 u){ return bfu(u & 0xffffu); }
__device__ __forceinline__ float bf_hi(u32 u){ return bfu(u >> 16); }
__device__ __forceinline__ float bf16f(u16 u){ return bfu((u32)u); }
__device__ __forceinline__ u16 f2bf(float f){
    union{float f; u32 i;} w; w.f = f;
    u32 r = (w.i + 0x7fffu + ((w.i >> 16) & 1u)) >> 16;   // RNE
    return (u16)r;
}
__device__ __forceinline__ u32 pack2(float lo, float hi){
    return (u32)f2bf(lo) | ((u32)f2bf(hi) << 16);
}

template<int IS32>
__device__ __forceinline__ float ldx(const void* p, int i){
    if (IS32) return ((const float*)p)[i];
    else      return bf16f(((const u16*)p)[i]);
}

// ---------------- dtype sniff: fp32 (1) vs bf16 (0) ----------------
__global__ void k_sniff(const u32* __restrict__ x, int* __restrict__ flag){
    __shared__ int cnt[256];
    int t = threadIdx.x;
    int bad = 0;
    for (int i = t; i < 512; i += 256){
        u32 w = x[i];
        u32 lo = w & 0xffffu;
        u32 e = (lo >> 7) & 0xffu;
        bool sane = (lo == 0u) || (lo == 0x8000u) || (e >= 85u && e <= 133u);
        if (!sane) bad++;
    }
    cnt[t] = bad; __syncthreads();
    for (int s = 128; s > 0; s >>= 1){
        if (t < s) cnt[t] += cnt[t+s];
        __syncthreads();
    }
    if (t == 0) flag[0] = (cnt[0] > 100) ? 1 : 0;
}

// ---------------- CSR build (dtype-independent) ----------------

__global__ void k_deg(const int* __restrict__ dst, int* __restrict__ deg){
    int stride = gridDim.x * blockDim.x;
    for (int i = blockIdx.x*blockDim.x + threadIdx.x; i < NE; i += stride){
        int d = dst[i];
        if ((unsigned)d < (unsigned)NN) atomicAdd(&deg[d], 1);
    }
}

__global__ void k_csum(const int* __restrict__ deg, int* __restrict__ csum){
    __shared__ int sdata[256];
    int t = threadIdx.x;
    int idx = blockIdx.x*256 + t;
    sdata[t] = (idx < NN) ? deg[idx] : 0;
    __syncthreads();
    for (int s = 128; s > 0; s >>= 1){
        if (t < s) sdata[t] += sdata[t+s];
        __syncthreads();
    }
    if (t == 0) csum[blockIdx.x] = sdata[0];
}

__global__ void k_scan_chunks(const int* __restrict__ csum, int* __restrict__ coff){
    __shared__ int s[512];
    int t = threadIdx.x;
    int v = (t < NCHUNK) ? csum[t] : 0;
    s[t] = v; __syncthreads();
    int x = v;
    for (int off = 1; off < 512; off <<= 1){
        int y = (t >= off) ? s[t-off] : 0;
        __syncthreads();
        x += y; s[t] = x;
        __syncthreads();
    }
    if (t < NCHUNK) coff[t] = x - v;   // exclusive
}

__global__ void k_rowptr(const int* __restrict__ deg, const int* __restrict__ coff,
                         int* __restrict__ row_ptr){
    __shared__ int s[256];
    int t = threadIdx.x, b = blockIdx.x;
    int idx = b*256 + t;
    int v = (idx < NN) ? deg[idx] : 0;
    s[t] = v; __syncthreads();
    int x = v;
    for (int off = 1; off < 256; off <<= 1){
        int y = (t >= off) ? s[t-off] : 0;
        __syncthreads();
        x += y; s[t] = x;
        __syncthreads();
    }
    if (idx < NN)       row_ptr[idx] = coff[b] + x - v;   // exclusive
    if (idx == NN - 1)  row_ptr[NN]  = coff[b] + x;       // total = NE
}

__global__ void k_scatter(const int* __restrict__ src, const int* __restrict__ dst,
                          const int* __restrict__ row_ptr, int* __restrict__ fill,
                          int2* __restrict__ pair_sorted){
    int stride = gridDim.x * blockDim.x;
    for (int i = blockIdx.x*blockDim.x + threadIdx.x; i < NE; i += stride){
        int d = dst[i];
        if ((unsigned)d >= (unsigned)NN) continue;
        int p = row_ptr[d] + atomicAdd(&fill[d], 1);
        if ((unsigned)p < (unsigned)NE){
            int s = src[i];
            if ((unsigned)s >= (unsigned)NN) s = 0;
            pair_sorted[p] = make_int2(s, i);
        }
    }
}

// ---------------- edge-attr reorder into p-sorted order (bf16 packed) ----------------
template<int IS32>
__global__ __launch_bounds__(256) void k_reorder(const int2* __restrict__ pair_sorted,
                                                 const void* __restrict__ ea,
                                                 const int* __restrict__ flg,
                                                 uint4* __restrict__ ea_srt){
    if (flg[0] != IS32) return;
    int stride = gridDim.x * blockDim.x;
    for (int p = blockIdx.x*blockDim.x + threadIdx.x; p < NE; p += stride){
        int eid = pair_sorted[p].y;
        if ((unsigned)eid >= (unsigned)NE) eid = 0;
        uint4 o0, o1;
        if (IS32){
            const float4* er = (const float4*)ea + (size_t)eid*4;
            float4 u0 = er[0], u1 = er[1], u2 = er[2], u3 = er[3];
            o0.x = pack2(u0.x, u0.y); o0.y = pack2(u0.z, u0.w);
            o0.z = pack2(u1.x, u1.y); o0.w = pack2(u1.z, u1.w);
            o1.x = pack2(u2.x, u2.y); o1.y = pack2(u2.z, u2.w);
            o1.z = pack2(u3.x, u3.y); o1.w = pack2(u3.z, u3.w);
        } else {
            const uint4* er = (const uint4*)ea + (size_t)eid*2;
            o0 = er[0]; o1 = er[1];
        }
        ea_srt[(size_t)p*2 + 0] = o0;
        ea_srt[(size_t)p*2 + 1] = o1;
    }
}

// ---------------- input projection: h = x @ src_w + src_b (bf16 out, dword-packed store) ----------------
template<int IS32>
__global__ __launch_bounds__(256) void k_proj(const void* __restrict__ x,
                                              const void* __restrict__ w,
                                              const void* __restrict__ b,
                                              const int* __restrict__ flg,
                                              u16* __restrict__ h){
    if (flg[0] != IS32) return;
    int lane = threadIdx.x & 63;
    int wid  = (blockIdx.x*256 + threadIdx.x) >> 6;
    int nw   = (gridDim.x*256) >> 6;
    float wr[32];
    #pragma unroll
    for (int k = 0; k < 32; k++) wr[k] = ldx<IS32>(w, k*64 + lane);
    float bias = ldx<IS32>(b, lane);
    for (int node = wid; node < NN; node += nw){
        float acc = bias;
        if (IS32){
            const float* xr = (const float*)x + (size_t)node*32;
            #pragma unroll
            for (int k = 0; k < 32; k++) acc = fmaf(xr[k], wr[k], acc);
        } else {
            const u16* xr = (const u16*)x + (size_t)node*32;
            #pragma unroll
            for (int k = 0; k < 32; k++) acc = fmaf(bf16f(xr[k]), wr[k], acc);
        }
        float accn = __shfl_xor(acc, 1, 64);
        if (!(lane & 1))
            ((u32*)h)[(size_t)node*32 + (lane >> 1)] = pack2(acc, accn);
    }
}

// 16-channel dot of one bf16-packed edge-attr row with per-lane ew column
__device__ __forceinline__ float edot(uint4 a, uint4 b, const float* ewr, float ebr){
    float e = ebr;
    e = fmaf(bf_lo(a.x), ewr[0],  e); e = fmaf(bf_hi(a.x), ewr[1],  e);
    e = fmaf(bf_lo(a.y), ewr[2],  e); e = fmaf(bf_hi(a.y), ewr[3],  e);
    e = fmaf(bf_lo(a.z), ewr[4],  e); e = fmaf(bf_hi(a.z), ewr[5],  e);
    e = fmaf(bf_lo(a.w), ewr[6],  e); e = fmaf(bf_hi(a.w), ewr[7],  e);
    e = fmaf(bf_lo(b.x), ewr[8],  e); e = fmaf(bf_hi(b.x), ewr[9],  e);
    e = fmaf(bf_lo(b.y), ewr[10], e); e = fmaf(bf_hi(b.y), ewr[11], e);
    e = fmaf(bf_lo(b.z), ewr[12], e); e = fmaf(bf_hi(b.z), ewr[13], e);
    e = fmaf(bf_lo(b.w), ewr[14], e); e = fmaf(bf_hi(b.w), ewr[15], e);
    return e;
}

// ---------------- fused GENConv layer (production — identical to round 3) ----------------
template<int IS32>
__global__ __launch_bounds__(256, 4) void k_layer(
    const u16*   __restrict__ h_in,
    const int*   __restrict__ row_ptr,
    const int2*  __restrict__ pair_sorted,
    const uint4* __restrict__ ea_srt,
    const void* __restrict__ ew, const void* __restrict__ eb,
    const void* __restrict__ w1, const void* __restrict__ b1,
    const void* __restrict__ g,  const void* __restrict__ bb,
    const void* __restrict__ w2, const void* __restrict__ b2,
    const int* __restrict__ flg,
    u16* __restrict__ h_out)
{
    if (flg[0] != IS32) return;

    __shared__ u32 w1p[64*64];        // lo=w1[k][c], hi=w1[k][c+64]   (16 KB)
    __shared__ u32 w2p[64*64];        // lo=w2[j][c], hi=w2[j+64][c]   (16 KB)
    __shared__ u32 tbuf[4*2*256];     // per-wave double-buffered 8x128B transpose tile (8 KB)

    int t = threadIdx.x;
    for (int i = t; i < 64*64; i += 256){
        int k = i >> 6, c = i & 63;
        u32 lo1, hi1, lo2, hi2;
        if (IS32){
            lo1 = f2bf(((const float*)w1)[k*128 + c]);
            hi1 = f2bf(((const float*)w1)[k*128 + c + 64]);
            lo2 = f2bf(((const float*)w2)[k*64 + c]);
            hi2 = f2bf(((const float*)w2)[(k+64)*64 + c]);
        } else {
            lo1 = ((const u16*)w1)[k*128 + c];
            hi1 = ((const u16*)w1)[k*128 + c + 64];
            lo2 = ((const u16*)w2)[k*64 + c];
            hi2 = ((const u16*)w2)[(k+64)*64 + c];
        }
        w1p[i] = lo1 | (hi1 << 16);
        w2p[i] = lo2 | (hi2 << 16);
    }
    __syncthreads();

    int lane = t & 63;
    int wslot = t >> 6;
    u32* tb0 = &tbuf[wslot*512];
    int wid  = (blockIdx.x*256 + t) >> 6;
    int nw   = (gridDim.x*256) >> 6;

    float ewr[16];
    #pragma unroll
    for (int k = 0; k < 16; k++) ewr[k] = ldx<IS32>(ew, k*64 + lane);
    float ebr = ldx<IS32>(eb, lane);
    const float BNS = 0.9999950000374997f;   // 1/sqrt(1+1e-5)
    float b1a = ldx<IS32>(b1, lane), b1b = ldx<IS32>(b1, lane+64);
    float ga  = ldx<IS32>(g, lane)*BNS,  gb  = ldx<IS32>(g, lane+64)*BNS;
    float bba = ldx<IS32>(bb, lane),     bbb = ldx<IS32>(bb, lane+64);
    float b2r = ldx<IS32>(b2, lane);

    int elane = lane >> 3;
    int eq    = lane & 7;

    for (int node = wid; node < NN; node += nw){
        int p0 = row_ptr[node], p1 = row_ptr[node+1];
        if (p0 < 0) p0 = 0;
        if (p1 > NE) p1 = NE;
        u32 hw_ = ((const u32*)h_in)[(size_t)node*32 + (lane >> 1)];
        float hself = (lane & 1) ? bf_hi(hw_) : bf_lo(hw_);

        float m = -1e30f, sw = 0.f, swm = 0.f;

        for (int base = p0; base < p1; base += 64){
            int nch = p1 - base; if (nch > 64) nch = 64;
            int sidx = 0;
            if (lane < nch) sidx = pair_sorted[base + lane].x;

            int ngr = (nch + 7) >> 3;
            int slot0 = elane; if (slot0 >= nch) slot0 = nch - 1;
            int s_g   = __shfl(sidx, slot0, 64);
            uint4 hv  = ((const uint4*)h_in)[(size_t)s_g*8 + eq];

            for (int gidx = 0; gidx < ngr; ++gidx){
                uint4 hvn = hv;
                if (gidx + 1 < ngr){
                    int sl = (gidx+1)*8 + elane; if (sl >= nch) sl = nch - 1;
                    int sn = __shfl(sidx, sl, 64);
                    hvn = ((const uint4*)h_in)[(size_t)sn*8 + eq];
                }
                u32* lb = tb0 + ((gidx & 1) << 8);
                ((uint4*)lb)[lane] = hv;
                float hr[8];
                #pragma unroll
                for (int e = 0; e < 8; e++){
                    u32 w = lb[e*32 + (lane >> 1)];
                    hr[e] = (lane & 1) ? bf_hi(w) : bf_lo(w);
                }

                #pragma unroll
                for (int sub = 0; sub < 2; ++sub){
                    int sbase = gidx*8 + sub*4;
                    int nv = nch - sbase;
                    if (nv > 0){
                        if (nv > 4) nv = 4;
                        int l0 = sbase;
                        int l1 = l0 + (nv > 1);
                        int l2 = l1 + (nv > 2);
                        int l3 = l2 + (nv > 3);
                        uint4 A0 = ea_srt[(size_t)(base+l0)*2], B0 = ea_srt[(size_t)(base+l0)*2+1];
                        uint4 A1 = ea_srt[(size_t)(base+l1)*2], B1 = ea_srt[(size_t)(base+l1)*2+1];
                        uint4 A2 = ea_srt[(size_t)(base+l2)*2], B2 = ea_srt[(size_t)(base+l2)*2+1];
                        uint4 A3 = ea_srt[(size_t)(base+l3)*2], B3 = ea_srt[(size_t)(base+l3)*2+1];

                        float v0 = fmaxf(hr[sub*4+0] + edot(A0, B0, ewr, ebr), 0.f) + 1e-7f;
                        float v1 = fmaxf(hr[sub*4+1] + edot(A1, B1, ewr, ebr), 0.f) + 1e-7f;
                        float v2 = fmaxf(hr[sub*4+2] + edot(A2, B2, ewr, ebr), 0.f) + 1e-7f;
                        float v3 = fmaxf(hr[sub*4+3] + edot(A3, B3, ewr, ebr), 0.f) + 1e-7f;

                        float vm = v0;
                        if (nv > 1) vm = fmaxf(vm, v1);
                        if (nv > 2) vm = fmaxf(vm, v2);
                        if (nv > 3) vm = fmaxf(vm, v3);
                        float nm = fmaxf(m, vm);
                        float sc = __expf(m - nm);
                        sw *= sc; swm *= sc;
                        float pw;
                        pw = __expf(v0 - nm); sw += pw; swm += pw*v0;
                        if (nv > 1){ pw = __expf(v1 - nm); sw += pw; swm += pw*v1; }
                        if (nv > 2){ pw = __expf(v2 - nm); sw += pw; swm += pw*v2; }
                        if (nv > 3){ pw = __expf(v3 - nm); sw += pw; swm += pw*v3; }
                        m = nm;
                    }
                }
                hv = hvn;
            }
        }
        float agg = (sw > 0.f) ? (swm / sw) : 0.f;
        float out = agg + hself;

        float acc1 = b1a, acc2 = b1b;
        #pragma unroll
        for (int k = 0; k < 64; k++){
            float ok = __shfl(out, k, 64);
            u32 wp = w1p[k*64 + lane];
            acc1 = fmaf(ok, bf_lo(wp), acc1);
            acc2 = fmaf(ok, bf_hi(wp), acc2);
        }
        float hh1 = fmaxf(fmaf(acc1, ga, bba), 0.f);
        float hh2 = fmaxf(fmaf(acc2, gb, bbb), 0.f);
        float acc = b2r;
        #pragma unroll
        for (int j = 0; j < 64; j++){
            float a1 = __shfl(hh1, j, 64);
            float a2 = __shfl(hh2, j, 64);
            u32 wp = w2p[j*64 + lane];
            acc = fmaf(a1, bf_lo(wp), acc);
            acc = fmaf(a2, bf_hi(wp), acc);
        }
        float vfin = fmaxf(acc, 0.f);
        float vnext = __shfl_xor(vfin, 1, 64);
        if (!(lane & 1))
            ((u32*)h_out)[(size_t)node*32 + (lane >> 1)] = pack2(vfin, vnext);
    }
}

// ================= DIAGNOSTIC ABLATIONS (write only to dead scratch) =================
// Per-dispatch dur_us from rocprof discriminates: gather-latency vs stream-bytes vs
// loop-structure vs slow-workspace. Production output is unaffected.

// V1: edge loop WITHOUT the random h[src] gather (pair + ea + softmax kept)
__global__ __launch_bounds__(256, 4) void k_abl_nogather(
    const u16* __restrict__ h_in, const int* __restrict__ row_ptr,
    const int2* __restrict__ pair_sorted, const uint4* __restrict__ ea_srt,
    const u16* __restrict__ ew, const u16* __restrict__ eb,
    u16* __restrict__ outb)
{
    int t = threadIdx.x, lane = t & 63;
    int wid = (blockIdx.x*256 + t) >> 6, nw = (gridDim.x*256) >> 6;
    float ewr[16];
    #pragma unroll
    for (int k = 0; k < 16; k++) ewr[k] = bf16f(ew[k*64 + lane]);
    float ebr = bf16f(eb[lane]);
    for (int node = wid; node < NN; node += nw){
        int p0 = row_ptr[node], p1 = row_ptr[node+1];
        if (p0 < 0) p0 = 0;
        if (p1 > NE) p1 = NE;
        u32 hw_ = ((const u32*)h_in)[(size_t)node*32 + (lane >> 1)];
        float hself = (lane & 1) ? bf_hi(hw_) : bf_lo(hw_);
        float m = -1e30f, sw = 0.f, swm = 0.f;
        for (int base = p0; base < p1; base += 64){
            int nch = p1 - base; if (nch > 64) nch = 64;
            int sidx = 0;
            if (lane < nch) sidx = pair_sorted[base + lane].x;
            asm volatile("" :: "v"(sidx));          // keep the pair load live (rule #17)
            for (int j = 0; j < nch; j += 4){
                int nv = nch - j; if (nv > 4) nv = 4;
                int l0 = j, l1 = l0 + (nv > 1), l2 = l1 + (nv > 2), l3 = l2 + (nv > 3);
                uint4 A0 = ea_srt[(size_t)(base+l0)*2], B0 = ea_srt[(size_t)(base+l0)*2+1];
                uint4 A1 = ea_srt[(size_t)(base+l1)*2], B1 = ea_srt[(size_t)(base+l1)*2+1];
                uint4 A2 = ea_srt[(size_t)(base+l2)*2], B2 = ea_srt[(size_t)(base+l2)*2+1];
                uint4 A3 = ea_srt[(size_t)(base+l3)*2], B3 = ea_srt[(size_t)(base+l3)*2+1];
                float v0 = fmaxf(hself + edot(A0, B0, ewr, ebr), 0.f) + 1e-7f;
                float v1 = fmaxf(hself + edot(A1, B1, ewr, ebr), 0.f) + 1e-7f;
                float v2 = fmaxf(hself + edot(A2, B2, ewr, ebr), 0.f) + 1e-7f;
                float v3 = fmaxf(hself + edot(A3, B3, ewr, ebr), 0.f) + 1e-7f;
                float vm = v0;
                if (nv > 1) vm = fmaxf(vm, v1);
                if (nv > 2) vm = fmaxf(vm, v2);
                if (nv > 3) vm = fmaxf(vm, v3);
                float nm = fmaxf(m, vm);
                float sc = __expf(m - nm);
                sw *= sc; swm *= sc;
                float pw;
                pw = __expf(v0 - nm); sw += pw; swm += pw*v0;
                if (nv > 1){ pw = __expf(v1 - nm); sw += pw; swm += pw*v1; }
                if (nv > 2){ pw = __expf(v2 - nm); sw += pw; swm += pw*v2; }
                if (nv > 3){ pw = __expf(v3 - nm); sw += pw; swm += pw*v3; }
                m = nm;
            }
        }
        float agg = (sw > 0.f) ? (swm / sw) : 0.f;
        outb[(size_t)node*64 + lane] = f2bf(agg + hself);
    }
}

// V2: edge loop WITHOUT ea reads (wide gather + LDS transpose + softmax kept)
__global__ __launch_bounds__(256, 4) void k_abl_noea(
    const u16* __restrict__ h_in, const int* __restrict__ row_ptr,
    const int2* __restrict__ pair_sorted, u16* __restrict__ outb)
{
    __shared__ u32 tbuf[4*2*256];
    int t = threadIdx.x, lane = t & 63, wslot = t >> 6;
    u32* tb0 = &tbuf[wslot*512];
    int wid = (blockIdx.x*256 + t) >> 6, nw = (gridDim.x*256) >> 6;
    int elane = lane >> 3, eq = lane & 7;
    for (int node = wid; node < NN; node += nw){
        int p0 = row_ptr[node], p1 = row_ptr[node+1];
        if (p0 < 0) p0 = 0;
        if (p1 > NE) p1 = NE;
        u32 hw_ = ((const u32*)h_in)[(size_t)node*32 + (lane >> 1)];
        float hself = (lane & 1) ? bf_hi(hw_) : bf_lo(hw_);
        float m = -1e30f, sw = 0.f, swm = 0.f;
        for (int base = p0; base < p1; base += 64){
            int nch = p1 - base; if (nch > 64) nch = 64;
            int sidx = 0;
            if (lane < nch) sidx = pair_sorted[base + lane].x;
            int ngr = (nch + 7) >> 3;
            int slot0 = elane; if (slot0 >= nch) slot0 = nch - 1;
            int s_g = __shfl(sidx, slot0, 64);
            uint4 hv = ((const uint4*)h_in)[(size_t)s_g*8 + eq];
            for (int gidx = 0; gidx < ngr; ++gidx){
                uint4 hvn = hv;
                if (gidx + 1 < ngr){
                    int sl = (gidx+1)*8 + elane; if (sl >= nch) sl = nch - 1;
                    int sn = __shfl(sidx, sl, 64);
                    hvn = ((const uint4*)h_in)[(size_t)sn*8 + eq];
                }
                u32* lb = tb0 + ((gidx & 1) << 8);
                ((uint4*)lb)[lane] = hv;
                float hr[8];
                #pragma unroll
                for (int e = 0; e < 8; e++){
                    u32 w = lb[e*32 + (lane >> 1)];
                    hr[e] = (lane & 1) ? bf_hi(w) : bf_lo(w);
                }
                #pragma unroll
                for (int sub = 0; sub < 2; ++sub){
                    int sbase = gidx*8 + sub*4;
                    int nv = nch - sbase;
                    if (nv > 0){
                        if (nv > 4) nv = 4;
                        float v0 = fmaxf(hr[sub*4+0] + 0.1f, 0.f) + 1e-7f;
                        float v1 = fmaxf(hr[sub*4+1] + 0.1f, 0.f) + 1e-7f;
                        float v2 = fmaxf(hr[sub*4+2] + 0.1f, 0.f) + 1e-7f;
                        float v3 = fmaxf(hr[sub*4+3] + 0.1f, 0.f) + 1e-7f;
                        float vm = v0;
                        if (nv > 1) vm = fmaxf(vm, v1);
                        if (nv > 2) vm = fmaxf(vm, v2);
                        if (nv > 3) vm = fmaxf(vm, v3);
                        float nm = fmaxf(m, vm);
                        float sc = __expf(m - nm);
                        sw *= sc; swm *= sc;
                        float pw;
                        pw = __expf(v0 - nm); sw += pw; swm += pw*v0;
                        if (nv > 1){ pw = __expf(v1 - nm); sw += pw; swm += pw*v1; }
                        if (nv > 2){ pw = __expf(v2 - nm); sw += pw; swm += pw*v2; }
                        if (nv > 3){ pw = __expf(v3 - nm); sw += pw; swm += pw*v3; }
                        m = nm;
                    }
                }
                hv = hvn;
            }
        }
        float agg = (sw > 0.f) ? (swm / sw) : 0.f;
        outb[(size_t)node*64 + lane] = f2bf(agg + hself);
    }
}

// V3: MLP only (no edge loop)
__global__ __launch_bounds__(256, 4) void k_abl_mlponly(
    const u16* __restrict__ h_in,
    const u16* __restrict__ w1, const u16* __restrict__ b1,
    const u16* __restrict__ g,  const u16* __restrict__ bb,
    const u16* __restrict__ w2, const u16* __restrict__ b2,
    u16* __restrict__ outb)
{
    __shared__ u32 w1p[64*64];
    __shared__ u32 w2p[64*64];
    int t = threadIdx.x;
    for (int i = t; i < 64*64; i += 256){
        int k = i >> 6, c = i & 63;
        w1p[i] = (u32)w1[k*128 + c] | ((u32)w1[k*128 + c + 64] << 16);
        w2p[i] = (u32)w2[k*64 + c]  | ((u32)w2[(k+64)*64 + c] << 16);
    }
    __syncthreads();
    int lane = t & 63;
    int wid = (blockIdx.x*256 + t) >> 6, nw = (gridDim.x*256) >> 6;
    const float BNS = 0.9999950000374997f;
    float b1a = bf16f(b1[lane]), b1b = bf16f(b1[lane+64]);
    float ga  = bf16f(g[lane])*BNS,  gb  = bf16f(g[lane+64])*BNS;
    float bba = bf16f(bb[lane]),     bbb = bf16f(bb[lane+64]);
    float b2r = bf16f(b2[lane]);
    for (int node = wid; node < NN; node += nw){
        u32 hw_ = ((const u32*)h_in)[(size_t)node*32 + (lane >> 1)];
        float out = (lane & 1) ? bf_hi(hw_) : bf_lo(hw_);
        float acc1 = b1a, acc2 = b1b;
        #pragma unroll
        for (int k = 0; k < 64; k++){
            float ok = __shfl(out, k, 64);
            u32 wp = w1p[k*64 + lane];
            acc1 = fmaf(ok, bf_lo(wp), acc1);
            acc2 = fmaf(ok, bf_hi(wp), acc2);
        }
        float hh1 = fmaxf(fmaf(acc1, ga, bba), 0.f);
        float hh2 = fmaxf(fmaf(acc2, gb, bbb), 0.f);
        float acc = b2r;
        #pragma unroll
        for (int j = 0; j < 64; j++){
            float a1 = __shfl(hh1, j, 64);
            float a2 = __shfl(hh2, j, 64);
            u32 wp = w2p[j*64 + lane];
            acc = fmaf(a1, bf_lo(wp), acc);
            acc = fmaf(a2, bf_hi(wp), acc);
        }
        float vfin = fmaxf(acc, 0.f);
        float vnext = __shfl_xor(vfin, 1, 64);
        if (!(lane & 1))
            ((u32*)outb)[(size_t)node*32 + (lane >> 1)] = pack2(vfin, vnext);
    }
}

// pure 16B-stride stream read: measures achievable streaming BW of the given buffer
__global__ __launch_bounds__(256) void k_stream(const uint4* __restrict__ p, long n16,
                                                float* __restrict__ sum){
    uint4 acc = make_uint4(0,0,0,0);
    long stride = (long)gridDim.x * blockDim.x;
    for (long i = (long)blockIdx.x*blockDim.x + threadIdx.x; i < n16; i += stride){
        uint4 v = p[i];
        acc.x += v.x; acc.y += v.y; acc.z += v.z; acc.w += v.w;
    }
    u32 s = acc.x ^ acc.y ^ acc.z ^ acc.w;
    sum[(blockIdx.x*256 + threadIdx.x) & 2047] = (float)s;   // keep-alive store (values unused)
}

// ---------------- head: out = concat(h, gf) @ head_w + head_b  (FP32 OUT) ----------------
template<int IS32>
__global__ __launch_bounds__(256) void k_head(const u16* __restrict__ h,
                                              const void* __restrict__ gf,
                                              const int* __restrict__ ngp,
                                              const void* __restrict__ hw,
                                              const void* __restrict__ hb,
                                              const int* __restrict__ flg,
                                              float* __restrict__ out){
    if (flg[0] != IS32) return;
    int lane = threadIdx.x & 63;
    int wid  = (blockIdx.x*256 + threadIdx.x) >> 6;
    int nw   = (gridDim.x*256) >> 6;
    int dw = lane & 31;
    bool active = lane < 32;
    float wc0 = active ? ldx<IS32>(hw, 2*dw)     : 0.f;
    float wc1 = active ? ldx<IS32>(hw, 2*dw + 1) : 0.f;
    float w64 = ldx<IS32>(hw, 64), w65 = ldx<IS32>(hw, 65);
    float bias = ldx<IS32>(hb, 0);
    int ng  = ngp[0];
    if (ng <= 0) ng = 1;
    int npg = NN / ng;
    if (npg <= 0) npg = 1;
    for (int node = wid; node < NN; node += nw){
        float v = 0.f;
        if (active){
            u32 w = ((const u32*)h)[(size_t)node*32 + dw];
            v = bf_lo(w)*wc0 + bf_hi(w)*wc1;
        }
        #pragma unroll
        for (int off = 32; off > 0; off >>= 1) v += __shfl_xor(v, off, 64);
        if (lane == 0){
            int gidx = node / npg, r = node - gidx*npg;
            float g0 = ldx<IS32>(gf, (gidx*2 + 0)*npg + r);
            float g1 = ldx<IS32>(gf, (gidx*2 + 1)*npg + r);
            out[node] = v + g0*w64 + g1*w65 + bias;
        }
    }
}

// ---------------- launch ----------------
extern "C" void kernel_launch(void* const* d_in, const int* in_sizes, int n_in,
                              void* d_out, int out_size, void* d_ws, size_t ws_size,
                              hipStream_t stream){
    const void* x    = d_in[0];
    const int*  ei   = (const int*)d_in[1];          // [2, NE]: row0=src, row1=dst
    const void* ea   = d_in[2];
    const int*  ngp  = (const int*)d_in[3];
    const void* gf   = d_in[4];
    const void* srcw = d_in[5];
    const void* srcb = d_in[6];
    const void* L[16];
    for (int i = 0; i < 16; i++) L[i] = d_in[7 + i];
    const void* headw = d_in[23];
    const void* headb = d_in[24];

    char* ws = (char*)d_ws;
    size_t off = 0;
    auto alloc = [&](size_t bytes) -> void* {
        void* p = ws + off;
        off += (bytes + 255) & ~size_t(255);
        return p;
    };
    u16* hA          = (u16*)  alloc((size_t)NN*64*2);    // 12.8 MB
    u16* hB          = (u16*)  alloc((size_t)NN*64*2);    // 12.8 MB (dead after layer1 -> diag scratch)
    int* row_ptr     = (int*)  alloc((size_t)(NN+1)*4);
    int* cnt         = (int*)  alloc((size_t)2*NN*4);     // deg | fill
    int* deg  = cnt;
    int* fill = cnt + NN;
    int* csum        = (int*)  alloc((size_t)NCHUNK*4);
    int* coff        = (int*)  alloc((size_t)NCHUNK*4);
    int* flg         = (int*)  alloc(256);
    int2* pair_sorted= (int2*) alloc((size_t)NE*8);       // 12.8 MB
    uint4* ea_srt    = (uint4*)alloc((size_t)NE*32);      // 51.2 MB (bf16 [NE,16], p-sorted)
    float* dsum      = (float*)alloc((size_t)2048*4);     // stream keep-alive sink
    // total ~= 91 MB

    hipMemsetAsync(cnt, 0, (size_t)2*NN*4, stream);

    const int* e_src = ei;
    const int* e_dst = ei + NE;

    k_sniff      <<<1, 256, 0, stream>>>((const u32*)x, flg);
    k_deg        <<<1024, 256, 0, stream>>>(e_dst, deg);
    k_csum       <<<NCHUNK, 256, 0, stream>>>(deg, csum);
    k_scan_chunks<<<1, 512, 0, stream>>>(csum, coff);
    k_rowptr     <<<NCHUNK, 256, 0, stream>>>(deg, coff, row_ptr);
    k_scatter    <<<1024, 256, 0, stream>>>(e_src, e_dst, row_ptr, fill, pair_sorted);

    k_reorder<1> <<<2048, 256, 0, stream>>>(pair_sorted, ea, flg, ea_srt);
    k_reorder<0> <<<2048, 256, 0, stream>>>(pair_sorted, ea, flg, ea_srt);

    k_proj<1>    <<<512, 256, 0, stream>>>(x, srcw, srcb, flg, hA);
    k_proj<0>    <<<512, 256, 0, stream>>>(x, srcw, srcb, flg, hA);

    k_layer<1>   <<<1024, 256, 0, stream>>>(hA, row_ptr, pair_sorted, ea_srt,
                    L[0], L[1], L[2], L[3], L[4], L[5], L[6], L[7], flg, hB);
    k_layer<0>   <<<1024, 256, 0, stream>>>(hA, row_ptr, pair_sorted, ea_srt,
                    L[0], L[1], L[2], L[3], L[4], L[5], L[6], L[7], flg, hB);

    k_layer<1>   <<<1024, 256, 0, stream>>>(hB, row_ptr, pair_sorted, ea_srt,
                    L[8], L[9], L[10], L[11], L[12], L[13], L[14], L[15], flg, hA);
    k_layer<0>   <<<1024, 256, 0, stream>>>(hB, row_ptr, pair_sorted, ea_srt,
                    L[8], L[9], L[10], L[11], L[12], L[13], L[14], L[15], flg, hA);

    k_head<1>    <<<512, 256, 0, stream>>>(hA, gf, ngp, headw, headb, flg, (float*)d_out);
    k_head<0>    <<<512, 256, 0, stream>>>(hA, gf, ngp, headw, headb, flg, (float*)d_out);

    // ---- diagnostics (write only to hB, which is dead after the second k_layer) ----
    k_abl_nogather<<<1024, 256, 0, stream>>>(hA, row_ptr, pair_sorted, ea_srt,
                    (const u16*)L[8], (const u16*)L[9], hB);
    k_abl_noea    <<<1024, 256, 0, stream>>>(hA, row_ptr, pair_sorted, hB);
    k_abl_mlponly <<<1024, 256, 0, stream>>>(hA,
                    (const u16*)L[10], (const u16*)L[11], (const u16*)L[12],
                    (const u16*)L[13], (const u16*)L[14], (const u16*)L[15], hB);
    k_stream      <<<2048, 256, 0, stream>>>(ea_srt, (long)NE*2, dsum);            // workspace stream
    k_stream      <<<2048, 256, 0, stream>>>((const uint4*)ea, (long)NE*2, dsum);  // input stream
}

// Round 5
// 5797.280 us; speedup vs baseline: 1.4093x; 1.4093x over previous
//
#include <hip/hip_runtime.h>
#include <hip/hip_bf16.h>

#define NN 100000
#define NE 1600000
#define NCHUNK 391   // ceil(100000/256)

typedef unsigned short u16;
typedef unsigned int   u32;

__device__ __forceinline__ float bfu(u32 v){ union{u32 i; float f;} w; w.i = v<<16; return w.f; }
__device__ __forceinline__ float bf_lo(u32 u){ return bfu(u & 0xffffu); }
__device__ __forceinline__ float bf_hi(u32 u){ return bfu(u >> 16); }
__device__ __forceinline__ float bf16f(u16 u){ return bfu((u32)u); }
__device__ __forceinline__ u16 f2bf(float f){
    union{float f; u32 i;} w; w.f = f;
    u32 r = (w.i + 0x7fffu + ((w.i >> 16) & 1u)) >> 16;   // RNE
    return (u16)r;
}
__device__ __forceinline__ u32 pack2(float lo, float hi){
    return (u32)f2bf(lo) | ((u32)f2bf(hi) << 16);
}

template<int IS32>
__device__ __forceinline__ float ldx(const void* p, int i){
    if (IS32) return ((const float*)p)[i];
    else      return bf16f(((const u16*)p)[i]);
}

// ---------------- dtype sniff: fp32 (1) vs bf16 (0) ----------------
__global__ void k_sniff(const u32* __restrict__ x, int* __restrict__ flag){
    __shared__ int cnt[256];
    int t = threadIdx.x;
    int bad = 0;
    for (int i = t; i < 512; i += 256){
        u32 w = x[i];
        u32 lo = w & 0xffffu;
        u32 e = (lo >> 7) & 0xffu;
        bool sane = (lo == 0u) || (lo == 0x8000u) || (e >= 85u && e <= 133u);
        if (!sane) bad++;
    }
    cnt[t] = bad; __syncthreads();
    for (int s = 128; s > 0; s >>= 1){
        if (t < s) cnt[t] += cnt[t+s];
        __syncthreads();
    }
    if (t == 0) flag[0] = (cnt[0] > 100) ? 1 : 0;
}

// ---------------- CSR build (dtype-independent) ----------------

__global__ void k_deg(const int* __restrict__ dst, int* __restrict__ deg){
    int stride = gridDim.x * blockDim.x;
    for (int i = blockIdx.x*blockDim.x + threadIdx.x; i < NE; i += stride){
        int d = dst[i];
        if ((unsigned)d < (unsigned)NN) atomicAdd(&deg[d], 1);
    }
}

__global__ void k_csum(const int* __restrict__ deg, int* __restrict__ csum){
    __shared__ int sdata[256];
    int t = threadIdx.x;
    int idx = blockIdx.x*256 + t;
    sdata[t] = (idx < NN) ? deg[idx] : 0;
    __syncthreads();
    for (int s = 128; s > 0; s >>= 1){
        if (t < s) sdata[t] += sdata[t+s];
        __syncthreads();
    }
    if (t == 0) csum[blockIdx.x] = sdata[0];
}

__global__ void k_scan_chunks(const int* __restrict__ csum, int* __restrict__ coff){
    __shared__ int s[512];
    int t = threadIdx.x;
    int v = (t < NCHUNK) ? csum[t] : 0;
    s[t] = v; __syncthreads();
    int x = v;
    for (int off = 1; off < 512; off <<= 1){
        int y = (t >= off) ? s[t-off] : 0;
        __syncthreads();
        x += y; s[t] = x;
        __syncthreads();
    }
    if (t < NCHUNK) coff[t] = x - v;   // exclusive
}

__global__ void k_rowptr(const int* __restrict__ deg, const int* __restrict__ coff,
                         int* __restrict__ row_ptr){
    __shared__ int s[256];
    int t = threadIdx.x, b = blockIdx.x;
    int idx = b*256 + t;
    int v = (idx < NN) ? deg[idx] : 0;
    s[t] = v; __syncthreads();
    int x = v;
    for (int off = 1; off < 256; off <<= 1){
        int y = (t >= off) ? s[t-off] : 0;
        __syncthreads();
        x += y; s[t] = x;
        __syncthreads();
    }
    if (idx < NN)       row_ptr[idx] = coff[b] + x - v;   // exclusive
    if (idx == NN - 1)  row_ptr[NN]  = coff[b] + x;       // total = NE
}

__global__ void k_scatter(const int* __restrict__ src, const int* __restrict__ dst,
                          const int* __restrict__ row_ptr, int* __restrict__ fill,
                          int2* __restrict__ pair_sorted){
    int stride = gridDim.x * blockDim.x;
    for (int i = blockIdx.x*blockDim.x + threadIdx.x; i < NE; i += stride){
        int d = dst[i];
        if ((unsigned)d >= (unsigned)NN) continue;
        int p = row_ptr[d] + atomicAdd(&fill[d], 1);
        if ((unsigned)p < (unsigned)NE){
            int s = src[i];
            if ((unsigned)s >= (unsigned)NN) s = 0;
            pair_sorted[p] = make_int2(s, i);
        }
    }
}

// ---------------- edge-attr reorder into p-sorted order (bf16 packed) ----------------
template<int IS32>
__global__ __launch_bounds__(256) void k_reorder(const int2* __restrict__ pair_sorted,
                                                 const void* __restrict__ ea,
                                                 const int* __restrict__ flg,
                                                 uint4* __restrict__ ea_srt){
    if (flg[0] != IS32) return;
    int stride = gridDim.x * blockDim.x;
    for (int p = blockIdx.x*blockDim.x + threadIdx.x; p < NE; p += stride){
        int eid = pair_sorted[p].y;
        if ((unsigned)eid >= (unsigned)NE) eid = 0;
        uint4 o0, o1;
        if (IS32){
            const float4* er = (const float4*)ea + (size_t)eid*4;
            float4 u0 = er[0], u1 = er[1], u2 = er[2], u3 = er[3];
            o0.x = pack2(u0.x, u0.y); o0.y = pack2(u0.z, u0.w);
            o0.z = pack2(u1.x, u1.y); o0.w = pack2(u1.z, u1.w);
            o1.x = pack2(u2.x, u2.y); o1.y = pack2(u2.z, u2.w);
            o1.z = pack2(u3.x, u3.y); o1.w = pack2(u3.z, u3.w);
        } else {
            const uint4* er = (const uint4*)ea + (size_t)eid*2;
            o0 = er[0]; o1 = er[1];
        }
        ea_srt[(size_t)p*2 + 0] = o0;
        ea_srt[(size_t)p*2 + 1] = o1;
    }
}

// ---------------- input projection: h = x @ src_w + src_b (bf16 out, dword-packed store) ----------------
template<int IS32>
__global__ __launch_bounds__(256) void k_proj(const void* __restrict__ x,
                                              const void* __restrict__ w,
                                              const void* __restrict__ b,
                                              const int* __restrict__ flg,
                                              u16* __restrict__ h){
    if (flg[0] != IS32) return;
    int lane = threadIdx.x & 63;
    int wid  = (blockIdx.x*256 + threadIdx.x) >> 6;
    int nw   = (gridDim.x*256) >> 6;
    float wr[32];
    #pragma unroll
    for (int k = 0; k < 32; k++) wr[k] = ldx<IS32>(w, k*64 + lane);
    float bias = ldx<IS32>(b, lane);
    for (int node = wid; node < NN; node += nw){
        float acc = bias;
        if (IS32){
            const float* xr = (const float*)x + (size_t)node*32;
            #pragma unroll
            for (int k = 0; k < 32; k++) acc = fmaf(xr[k], wr[k], acc);
        } else {
            const u16* xr = (const u16*)x + (size_t)node*32;
            #pragma unroll
            for (int k = 0; k < 32; k++) acc = fmaf(bf16f(xr[k]), wr[k], acc);
        }
        float accn = __shfl_xor(acc, 1, 64);
        if (!(lane & 1))
            ((u32*)h)[(size_t)node*32 + (lane >> 1)] = pack2(acc, accn);
    }
}

// 16-channel dot of one bf16-packed edge-attr row with per-lane ew column
__device__ __forceinline__ float edot(uint4 a, uint4 b, const float* ewr, float ebr){
    float e = ebr;
    e = fmaf(bf_lo(a.x), ewr[0],  e); e = fmaf(bf_hi(a.x), ewr[1],  e);
    e = fmaf(bf_lo(a.y), ewr[2],  e); e = fmaf(bf_hi(a.y), ewr[3],  e);
    e = fmaf(bf_lo(a.z), ewr[4],  e); e = fmaf(bf_hi(a.z), ewr[5],  e);
    e = fmaf(bf_lo(a.w), ewr[6],  e); e = fmaf(bf_hi(a.w), ewr[7],  e);
    e = fmaf(bf_lo(b.x), ewr[8],  e); e = fmaf(bf_hi(b.x), ewr[9],  e);
    e = fmaf(bf_lo(b.y), ewr[10], e); e = fmaf(bf_hi(b.y), ewr[11], e);
    e = fmaf(bf_lo(b.z), ewr[12], e); e = fmaf(bf_hi(b.z), ewr[13], e);
    e = fmaf(bf_lo(b.w), ewr[14], e); e = fmaf(bf_hi(b.w), ewr[15], e);
    return e;
}

// ================= TWO-PASS FAST PATH =================
// Pass 1: edge-parallel message build in dst-slot order.
//   Sequential: pair_sorted, ea_srt, msg write. Random: one line-coalesced
//   128B h-row read per edge, latency hidden by independent iterations
//   (2-deep prefetch, 32 waves/CU, no LDS). Arithmetic identical to the
//   old fused kernel -> absmax unchanged.
template<int IS32>
__global__ __launch_bounds__(256) void k_msg(
    const u16*   __restrict__ h_in,
    const int2*  __restrict__ pair_sorted,
    const uint4* __restrict__ ea_srt,
    const void* __restrict__ ew, const void* __restrict__ eb,
    const int* __restrict__ flg,
    float* __restrict__ msg)
{
    if (flg[0] != IS32) return;
    int lane = threadIdx.x & 63;
    int w    = (blockIdx.x*256 + threadIdx.x) >> 6;
    int nw   = (gridDim.x*256) >> 6;
    float ewr[16];
    #pragma unroll
    for (int k = 0; k < 16; k++) ewr[k] = ldx<IS32>(ew, k*64 + lane);
    float ebr = ldx<IS32>(eb, lane);
    int per = (NE + nw - 1) / nw;
    int p0 = w * per;
    int p1 = p0 + per; if (p1 > NE) p1 = NE;
    if (p0 >= p1) return;
    // 2-deep software pipeline over contiguous slot span (src-locality irrelevant;
    // the point is MANY independent h-row loads in flight per CU)
    int s0 = pair_sorted[p0].x; if ((unsigned)s0 >= (unsigned)NN) s0 = 0;
    u32  hA = ((const u32*)h_in)[(size_t)s0*32 + (lane >> 1)];
    uint4 A0 = ea_srt[(size_t)p0*2], B0 = ea_srt[(size_t)p0*2 + 1];
    for (int p = p0; p < p1; ++p){
        u32 hc = hA; uint4 Ac = A0, Bc = B0;
        if (p + 1 < p1){
            int sn = pair_sorted[p+1].x; if ((unsigned)sn >= (unsigned)NN) sn = 0;
            hA = ((const u32*)h_in)[(size_t)sn*32 + (lane >> 1)];
            A0 = ea_srt[(size_t)(p+1)*2]; B0 = ea_srt[(size_t)(p+1)*2 + 1];
        }
        float hs = (lane & 1) ? bf_hi(hc) : bf_lo(hc);
        float e  = edot(Ac, Bc, ewr, ebr);
        float v  = fmaxf(hs + e, 0.f) + 1e-7f;
        msg[(size_t)p*64 + lane] = v;          // 256B coalesced sequential store
    }
}

// Pass 2: node-parallel softmax-reduce + MLP. ALL loads sequential:
//   per 4-row group, lanes load one float4 each = 4 contiguous msg rows (1KB),
//   LDS-transposed to lane=channel ([4][64] fp32, conflict-free), then the
//   same online softmax and MLP as the fused kernel.
template<int IS32>
__global__ __launch_bounds__(256, 4) void k_sm(
    const u16*   __restrict__ h_in,
    const int*   __restrict__ row_ptr,
    const float* __restrict__ msg,
    const void* __restrict__ w1, const void* __restrict__ b1,
    const void* __restrict__ g,  const void* __restrict__ bb,
    const void* __restrict__ w2, const void* __restrict__ b2,
    const int* __restrict__ flg,
    u16* __restrict__ h_out)
{
    if (flg[0] != IS32) return;

    __shared__ u32   w1p[64*64];     // 16 KB
    __shared__ u32   w2p[64*64];     // 16 KB
    __shared__ float tbuf[4*2*256];  // 4 waves x dbuf x [4][64] fp32 = 8 KB

    int t = threadIdx.x;
    for (int i = t; i < 64*64; i += 256){
        int k = i >> 6, c = i & 63;
        u32 lo1, hi1, lo2, hi2;
        if (IS32){
            lo1 = f2bf(((const float*)w1)[k*128 + c]);
            hi1 = f2bf(((const float*)w1)[k*128 + c + 64]);
            lo2 = f2bf(((const float*)w2)[k*64 + c]);
            hi2 = f2bf(((const float*)w2)[(k+64)*64 + c]);
        } else {
            lo1 = ((const u16*)w1)[k*128 + c];
            hi1 = ((const u16*)w1)[k*128 + c + 64];
            lo2 = ((const u16*)w2)[k*64 + c];
            hi2 = ((const u16*)w2)[(k+64)*64 + c];
        }
        w1p[i] = lo1 | (hi1 << 16);
        w2p[i] = lo2 | (hi2 << 16);
    }
    __syncthreads();

    int lane = t & 63;
    int wslot = t >> 6;
    float* tb0 = &tbuf[wslot*512];
    int wid = (blockIdx.x*256 + t) >> 6;
    int nw  = (gridDim.x*256) >> 6;

    const float BNS = 0.9999950000374997f;   // 1/sqrt(1+1e-5)
    float b1a = ldx<IS32>(b1, lane), b1b = ldx<IS32>(b1, lane+64);
    float ga  = ldx<IS32>(g, lane)*BNS,  gb  = ldx<IS32>(g, lane+64)*BNS;
    float bba = ldx<IS32>(bb, lane),     bbb = ldx<IS32>(bb, lane+64);
    float b2r = ldx<IS32>(b2, lane);

    int r = lane >> 4;     // row within 4-row group
    int q = lane & 15;     // float4 index within row

    for (int node = wid; node < NN; node += nw){
        int p0 = row_ptr[node], p1 = row_ptr[node+1];
        if (p0 < 0) p0 = 0;
        if (p1 > NE) p1 = NE;
        int nch = p1 - p0;
        u32 hw_ = ((const u32*)h_in)[(size_t)node*32 + (lane >> 1)];
        float hself = (lane & 1) ? bf_hi(hw_) : bf_lo(hw_);

        float m = -1e30f, sw = 0.f, swm = 0.f;
        if (nch > 0){
            int ngr = (nch + 3) >> 2;
            int rr = r; if (rr >= nch) rr = nch - 1;
            float4 mv = ((const float4*)msg)[(size_t)(p0 + rr)*16 + q];
            for (int gi = 0; gi < ngr; ++gi){
                float4 mvn = mv;
                if (gi + 1 < ngr){
                    int rn = (gi+1)*4 + r; if (rn >= nch) rn = nch - 1;
                    mvn = ((const float4*)msg)[(size_t)(p0 + rn)*16 + q];
                }
                float* lb = tb0 + ((gi & 1) << 8);
                ((float4*)lb)[lane] = mv;        // [4][64] row-major tile
                float v0 = lb[0*64 + lane];
                float v1 = lb[1*64 + lane];
                float v2 = lb[2*64 + lane];
                float v3 = lb[3*64 + lane];

                int nv = nch - gi*4; if (nv > 4) nv = 4;
                float vm = v0;
                if (nv > 1) vm = fmaxf(vm, v1);
                if (nv > 2) vm = fmaxf(vm, v2);
                if (nv > 3) vm = fmaxf(vm, v3);
                float nm = fmaxf(m, vm);
                float sc = __expf(m - nm);       // 0 on first group
                sw *= sc; swm *= sc;
                float pw;
                pw = __expf(v0 - nm); sw += pw; swm += pw*v0;
                if (nv > 1){ pw = __expf(v1 - nm); sw += pw; swm += pw*v1; }
                if (nv > 2){ pw = __expf(v2 - nm); sw += pw; swm += pw*v2; }
                if (nv > 3){ pw = __expf(v3 - nm); sw += pw; swm += pw*v3; }
                m = nm;
                mv = mvn;
            }
        }
        float agg = (sw > 0.f) ? (swm / sw) : 0.f;
        float out = agg + hself;

        // MLP: 64 -> 128 (BN + relu) -> 64, then outer relu
        float acc1 = b1a, acc2 = b1b;
        #pragma unroll
        for (int k = 0; k < 64; k++){
            float ok = __shfl(out, k, 64);
            u32 wp = w1p[k*64 + lane];
            acc1 = fmaf(ok, bf_lo(wp), acc1);
            acc2 = fmaf(ok, bf_hi(wp), acc2);
        }
        float hh1 = fmaxf(fmaf(acc1, ga, bba), 0.f);
        float hh2 = fmaxf(fmaf(acc2, gb, bbb), 0.f);
        float acc = b2r;
        #pragma unroll
        for (int j = 0; j < 64; j++){
            float a1 = __shfl(hh1, j, 64);
            float a2 = __shfl(hh2, j, 64);
            u32 wp = w2p[j*64 + lane];
            acc = fmaf(a1, bf_lo(wp), acc);
            acc = fmaf(a2, bf_hi(wp), acc);
        }
        float vfin = fmaxf(acc, 0.f);
        float vnext = __shfl_xor(vfin, 1, 64);
        if (!(lane & 1))
            ((u32*)h_out)[(size_t)node*32 + (lane >> 1)] = pack2(vfin, vnext);
    }
}

// ---------------- fused GENConv layer (FALLBACK — identical to round 3) ----------------
template<int IS32>
__global__ __launch_bounds__(256, 4) void k_layer(
    const u16*   __restrict__ h_in,
    const int*   __restrict__ row_ptr,
    const int2*  __restrict__ pair_sorted,
    const uint4* __restrict__ ea_srt,
    const void* __restrict__ ew, const void* __restrict__ eb,
    const void* __restrict__ w1, const void* __restrict__ b1,
    const void* __restrict__ g,  const void* __restrict__ bb,
    const void* __restrict__ w2, const void* __restrict__ b2,
    const int* __restrict__ flg,
    u16* __restrict__ h_out)
{
    if (flg[0] != IS32) return;

    __shared__ u32 w1p[64*64];
    __shared__ u32 w2p[64*64];
    __shared__ u32 tbuf[4*2*256];

    int t = threadIdx.x;
    for (int i = t; i < 64*64; i += 256){
        int k = i >> 6, c = i & 63;
        u32 lo1, hi1, lo2, hi2;
        if (IS32){
            lo1 = f2bf(((const float*)w1)[k*128 + c]);
            hi1 = f2bf(((const float*)w1)[k*128 + c + 64]);
            lo2 = f2bf(((const float*)w2)[k*64 + c]);
            hi2 = f2bf(((const float*)w2)[(k+64)*64 + c]);
        } else {
            lo1 = ((const u16*)w1)[k*128 + c];
            hi1 = ((const u16*)w1)[k*128 + c + 64];
            lo2 = ((const u16*)w2)[k*64 + c];
            hi2 = ((const u16*)w2)[(k+64)*64 + c];
        }
        w1p[i] = lo1 | (hi1 << 16);
        w2p[i] = lo2 | (hi2 << 16);
    }
    __syncthreads();

    int lane = t & 63;
    int wslot = t >> 6;
    u32* tb0 = &tbuf[wslot*512];
    int wid  = (blockIdx.x*256 + t) >> 6;
    int nw   = (gridDim.x*256) >> 6;

    float ewr[16];
    #pragma unroll
    for (int k = 0; k < 16; k++) ewr[k] = ldx<IS32>(ew, k*64 + lane);
    float ebr = ldx<IS32>(eb, lane);
    const float BNS = 0.9999950000374997f;
    float b1a = ldx<IS32>(b1, lane), b1b = ldx<IS32>(b1, lane+64);
    float ga  = ldx<IS32>(g, lane)*BNS,  gb  = ldx<IS32>(g, lane+64)*BNS;
    float bba = ldx<IS32>(bb, lane),     bbb = ldx<IS32>(bb, lane+64);
    float b2r = ldx<IS32>(b2, lane);

    int elane = lane >> 3;
    int eq    = lane & 7;

    for (int node = wid; node < NN; node += nw){
        int p0 = row_ptr[node], p1 = row_ptr[node+1];
        if (p0 < 0) p0 = 0;
        if (p1 > NE) p1 = NE;
        u32 hw_ = ((const u32*)h_in)[(size_t)node*32 + (lane >> 1)];
        float hself = (lane & 1) ? bf_hi(hw_) : bf_lo(hw_);

        float m = -1e30f, sw = 0.f, swm = 0.f;

        for (int base = p0; base < p1; base += 64){
            int nch = p1 - base; if (nch > 64) nch = 64;
            int sidx = 0;
            if (lane < nch) sidx = pair_sorted[base + lane].x;

            int ngr = (nch + 7) >> 3;
            int slot0 = elane; if (slot0 >= nch) slot0 = nch - 1;
            int s_g   = __shfl(sidx, slot0, 64);
            uint4 hv  = ((const uint4*)h_in)[(size_t)s_g*8 + eq];

            for (int gidx = 0; gidx < ngr; ++gidx){
                uint4 hvn = hv;
                if (gidx + 1 < ngr){
                    int sl = (gidx+1)*8 + elane; if (sl >= nch) sl = nch - 1;
                    int sn = __shfl(sidx, sl, 64);
                    hvn = ((const uint4*)h_in)[(size_t)sn*8 + eq];
                }
                u32* lb = tb0 + ((gidx & 1) << 8);
                ((uint4*)lb)[lane] = hv;
                float hr[8];
                #pragma unroll
                for (int e = 0; e < 8; e++){
                    u32 w = lb[e*32 + (lane >> 1)];
                    hr[e] = (lane & 1) ? bf_hi(w) : bf_lo(w);
                }

                #pragma unroll
                for (int sub = 0; sub < 2; ++sub){
                    int sbase = gidx*8 + sub*4;
                    int nv = nch - sbase;
                    if (nv > 0){
                        if (nv > 4) nv = 4;
                        int l0 = sbase;
                        int l1 = l0 + (nv > 1);
                        int l2 = l1 + (nv > 2);
                        int l3 = l2 + (nv > 3);
                        uint4 A0 = ea_srt[(size_t)(base+l0)*2], B0 = ea_srt[(size_t)(base+l0)*2+1];
                        uint4 A1 = ea_srt[(size_t)(base+l1)*2], B1 = ea_srt[(size_t)(base+l1)*2+1];
                        uint4 A2 = ea_srt[(size_t)(base+l2)*2], B2 = ea_srt[(size_t)(base+l2)*2+1];
                        uint4 A3 = ea_srt[(size_t)(base+l3)*2], B3 = ea_srt[(size_t)(base+l3)*2+1];

                        float v0 = fmaxf(hr[sub*4+0] + edot(A0, B0, ewr, ebr), 0.f) + 1e-7f;
                        float v1 = fmaxf(hr[sub*4+1] + edot(A1, B1, ewr, ebr), 0.f) + 1e-7f;
                        float v2 = fmaxf(hr[sub*4+2] + edot(A2, B2, ewr, ebr), 0.f) + 1e-7f;
                        float v3 = fmaxf(hr[sub*4+3] + edot(A3, B3, ewr, ebr), 0.f) + 1e-7f;

                        float vm = v0;
                        if (nv > 1) vm = fmaxf(vm, v1);
                        if (nv > 2) vm = fmaxf(vm, v2);
                        if (nv > 3) vm = fmaxf(vm, v3);
                        float nm = fmaxf(m, vm);
                        float sc = __expf(m - nm);
                        sw *= sc; swm *= sc;
                        float pw;
                        pw = __expf(v0 - nm); sw += pw; swm += pw*v0;
                        if (nv > 1){ pw = __expf(v1 - nm); sw += pw; swm += pw*v1; }
                        if (nv > 2){ pw = __expf(v2 - nm); sw += pw; swm += pw*v2; }
                        if (nv > 3){ pw = __expf(v3 - nm); sw += pw; swm += pw*v3; }
                        m = nm;
                    }
                }
                hv = hvn;
            }
        }
        float agg = (sw > 0.f) ? (swm / sw) : 0.f;
        float out = agg + hself;

        float acc1 = b1a, acc2 = b1b;
        #pragma unroll
        for (int k = 0; k < 64; k++){
            float ok = __shfl(out, k, 64);
            u32 wp = w1p[k*64 + lane];
            acc1 = fmaf(ok, bf_lo(wp), acc1);
            acc2 = fmaf(ok, bf_hi(wp), acc2);
        }
        float hh1 = fmaxf(fmaf(acc1, ga, bba), 0.f);
        float hh2 = fmaxf(fmaf(acc2, gb, bbb), 0.f);
        float acc = b2r;
        #pragma unroll
        for (int j = 0; j < 64; j++){
            float a1 = __shfl(hh1, j, 64);
            float a2 = __shfl(hh2, j, 64);
            u32 wp = w2p[j*64 + lane];
            acc = fmaf(a1, bf_lo(wp), acc);
            acc = fmaf(a2, bf_hi(wp), acc);
        }
        float vfin = fmaxf(acc, 0.f);
        float vnext = __shfl_xor(vfin, 1, 64);
        if (!(lane & 1))
            ((u32*)h_out)[(size_t)node*32 + (lane >> 1)] = pack2(vfin, vnext);
    }
}

// ---------------- head: out = concat(h, gf) @ head_w + head_b  (FP32 OUT) ----------------
template<int IS32>
__global__ __launch_bounds__(256) void k_head(const u16* __restrict__ h,
                                              const void* __restrict__ gf,
                                              const int* __restrict__ ngp,
                                              const void* __restrict__ hw,
                                              const void* __restrict__ hb,
                                              const int* __restrict__ flg,
                                              float* __restrict__ out){
    if (flg[0] != IS32) return;
    int lane = threadIdx.x & 63;
    int wid  = (blockIdx.x*256 + threadIdx.x) >> 6;
    int nw   = (gridDim.x*256) >> 6;
    int dw = lane & 31;
    bool active = lane < 32;
    float wc0 = active ? ldx<IS32>(hw, 2*dw)     : 0.f;
    float wc1 = active ? ldx<IS32>(hw, 2*dw + 1) : 0.f;
    float w64 = ldx<IS32>(hw, 64), w65 = ldx<IS32>(hw, 65);
    float bias = ldx<IS32>(hb, 0);
    int ng  = ngp[0];
    if (ng <= 0) ng = 1;
    int npg = NN / ng;
    if (npg <= 0) npg = 1;
    for (int node = wid; node < NN; node += nw){
        float v = 0.f;
        if (active){
            u32 w = ((const u32*)h)[(size_t)node*32 + dw];
            v = bf_lo(w)*wc0 + bf_hi(w)*wc1;
        }
        #pragma unroll
        for (int off = 32; off > 0; off >>= 1) v += __shfl_xor(v, off, 64);
        if (lane == 0){
            int gidx = node / npg, r = node - gidx*npg;
            float g0 = ldx<IS32>(gf, (gidx*2 + 0)*npg + r);
            float g1 = ldx<IS32>(gf, (gidx*2 + 1)*npg + r);
            out[node] = v + g0*w64 + g1*w65 + bias;
        }
    }
}

// ---------------- launch ----------------
extern "C" void kernel_launch(void* const* d_in, const int* in_sizes, int n_in,
                              void* d_out, int out_size, void* d_ws, size_t ws_size,
                              hipStream_t stream){
    const void* x    = d_in[0];
    const int*  ei   = (const int*)d_in[1];          // [2, NE]: row0=src, row1=dst
    const void* ea   = d_in[2];
    const int*  ngp  = (const int*)d_in[3];
    const void* gf   = d_in[4];
    const void* srcw = d_in[5];
    const void* srcb = d_in[6];
    const void* L[16];
    for (int i = 0; i < 16; i++) L[i] = d_in[7 + i];
    const void* headw = d_in[23];
    const void* headb = d_in[24];

    char* ws = (char*)d_ws;
    size_t off = 0;
    auto alloc = [&](size_t bytes) -> void* {
        void* p = ws + off;
        off += (bytes + 255) & ~size_t(255);
        return p;
    };
    // common allocations (both paths)
    u16* hA          = (u16*)  alloc((size_t)NN*64*2);    // 12.8 MB
    u16* hB          = (u16*)  alloc((size_t)NN*64*2);    // 12.8 MB
    int* row_ptr     = (int*)  alloc((size_t)(NN+1)*4);
    int* cnt         = (int*)  alloc((size_t)2*NN*4);     // deg | fill
    int* deg  = cnt;
    int* fill = cnt + NN;
    int* csum        = (int*)  alloc((size_t)NCHUNK*4);
    int* coff        = (int*)  alloc((size_t)NCHUNK*4);
    int* flg         = (int*)  alloc(256);
    int2* pair_sorted= (int2*) alloc((size_t)NE*8);       // 12.8 MB
    uint4* ea_srt    = (uint4*)alloc((size_t)NE*32);      // 51.2 MB
    size_t base_need = off;
    // fast-path only: fp32 message buffer [NE, 64] in dst-slot order
    size_t msg_bytes = (size_t)NE*64*4;                   // 409.6 MB
    bool fast = (ws_size >= base_need + msg_bytes + (1u<<20));
    float* msgbuf = fast ? (float*)alloc(msg_bytes) : nullptr;

    hipMemsetAsync(cnt, 0, (size_t)2*NN*4, stream);

    const int* e_src = ei;
    const int* e_dst = ei + NE;

    k_sniff      <<<1, 256, 0, stream>>>((const u32*)x, flg);
    k_deg        <<<1024, 256, 0, stream>>>(e_dst, deg);
    k_csum       <<<NCHUNK, 256, 0, stream>>>(deg, csum);
    k_scan_chunks<<<1, 512, 0, stream>>>(csum, coff);
    k_rowptr     <<<NCHUNK, 256, 0, stream>>>(deg, coff, row_ptr);
    k_scatter    <<<1024, 256, 0, stream>>>(e_src, e_dst, row_ptr, fill, pair_sorted);

    k_reorder<1> <<<2048, 256, 0, stream>>>(pair_sorted, ea, flg, ea_srt);
    k_reorder<0> <<<2048, 256, 0, stream>>>(pair_sorted, ea, flg, ea_srt);

    k_proj<1>    <<<512, 256, 0, stream>>>(x, srcw, srcb, flg, hA);
    k_proj<0>    <<<512, 256, 0, stream>>>(x, srcw, srcb, flg, hA);

    if (fast){
        // layer 0: hA -> hB
        k_msg<1> <<<2048, 256, 0, stream>>>(hA, pair_sorted, ea_srt, L[0], L[1], flg, msgbuf);
        k_msg<0> <<<2048, 256, 0, stream>>>(hA, pair_sorted, ea_srt, L[0], L[1], flg, msgbuf);
        k_sm<1>  <<<1024, 256, 0, stream>>>(hA, row_ptr, msgbuf,
                        L[2], L[3], L[4], L[5], L[6], L[7], flg, hB);
        k_sm<0>  <<<1024, 256, 0, stream>>>(hA, row_ptr, msgbuf,
                        L[2], L[3], L[4], L[5], L[6], L[7], flg, hB);
        // layer 1: hB -> hA
        k_msg<1> <<<2048, 256, 0, stream>>>(hB, pair_sorted, ea_srt, L[8], L[9], flg, msgbuf);
        k_msg<0> <<<2048, 256, 0, stream>>>(hB, pair_sorted, ea_srt, L[8], L[9], flg, msgbuf);
        k_sm<1>  <<<1024, 256, 0, stream>>>(hB, row_ptr, msgbuf,
                        L[10], L[11], L[12], L[13], L[14], L[15], flg, hA);
        k_sm<0>  <<<1024, 256, 0, stream>>>(hB, row_ptr, msgbuf,
                        L[10], L[11], L[12], L[13], L[14], L[15], flg, hA);
    } else {
        k_layer<1> <<<1024, 256, 0, stream>>>(hA, row_ptr, pair_sorted, ea_srt,
                        L[0], L[1], L[2], L[3], L[4], L[5], L[6], L[7], flg, hB);
        k_layer<0> <<<1024, 256, 0, stream>>>(hA, row_ptr, pair_sorted, ea_srt,
                        L[0], L[1], L[2], L[3], L[4], L[5], L[6], L[7], flg, hB);
        k_layer<1> <<<1024, 256, 0, stream>>>(hB, row_ptr, pair_sorted, ea_srt,
                        L[8], L[9], L[10], L[11], L[12], L[13], L[14], L[15], flg, hA);
        k_layer<0> <<<1024, 256, 0, stream>>>(hB, row_ptr, pair_sorted, ea_srt,
                        L[8], L[9], L[10], L[11], L[12], L[13], L[14], L[15], flg, hA);
    }

    k_head<1>    <<<512, 256, 0, stream>>>(hA, gf, ngp, headw, headb, flg, (float*)d_out);
    k_head<0>    <<<512, 256, 0, stream>>>(hA, gf, ngp, headw, headb, flg, (float*)d_out);
}

// Round 6
// 4831.257 us; speedup vs baseline: 1.6910x; 1.2000x over previous
//
#include <hip/hip_runtime.h>
#include <hip/hip_bf16.h>

#define NN 100000
#define NE 1600000
#define NCHUNK 391   // ceil(100000/256)

typedef unsigned short u16;
typedef unsigned int   u32;

__device__ __forceinline__ float bfu(u32 v){ union{u32 i; float f;} w; w.i = v<<16; return w.f; }
__device__ __forceinline__ float bf_lo(u32 u){ return bfu(u & 0xffffu); }
__device__ __forceinline__ float bf_hi(u32 u){ return bfu(u >> 16); }
__device__ __forceinline__ float bf16f(u16 u){ return bfu((u32)u); }
__device__ __forceinline__ u16 f2bf(float f){
    union{float f; u32 i;} w; w.f = f;
    u32 r = (w.i + 0x7fffu + ((w.i >> 16) & 1u)) >> 16;   // RNE
    return (u16)r;
}
__device__ __forceinline__ u32 pack2(float lo, float hi){
    return (u32)f2bf(lo) | ((u32)f2bf(hi) << 16);
}

template<int IS32>
__device__ __forceinline__ float ldx(const void* p, int i){
    if (IS32) return ((const float*)p)[i];
    else      return bf16f(((const u16*)p)[i]);
}

// ---------------- dtype sniff: fp32 (1) vs bf16 (0) ----------------
__global__ void k_sniff(const u32* __restrict__ x, int* __restrict__ flag){
    __shared__ int cnt[256];
    int t = threadIdx.x;
    int bad = 0;
    for (int i = t; i < 512; i += 256){
        u32 w = x[i];
        u32 lo = w & 0xffffu;
        u32 e = (lo >> 7) & 0xffu;
        bool sane = (lo == 0u) || (lo == 0x8000u) || (e >= 85u && e <= 133u);
        if (!sane) bad++;
    }
    cnt[t] = bad; __syncthreads();
    for (int s = 128; s > 0; s >>= 1){
        if (t < s) cnt[t] += cnt[t+s];
        __syncthreads();
    }
    if (t == 0) flag[0] = (cnt[0] > 100) ? 1 : 0;
}

// ---------------- CSR build (dtype-independent) ----------------

__global__ void k_deg(const int* __restrict__ dst, int* __restrict__ deg){
    int stride = gridDim.x * blockDim.x;
    for (int i = blockIdx.x*blockDim.x + threadIdx.x; i < NE; i += stride){
        int d = dst[i];
        if ((unsigned)d < (unsigned)NN) atomicAdd(&deg[d], 1);
    }
}

__global__ void k_csum(const int* __restrict__ deg, int* __restrict__ csum){
    __shared__ int sdata[256];
    int t = threadIdx.x;
    int idx = blockIdx.x*256 + t;
    sdata[t] = (idx < NN) ? deg[idx] : 0;
    __syncthreads();
    for (int s = 128; s > 0; s >>= 1){
        if (t < s) sdata[t] += sdata[t+s];
        __syncthreads();
    }
    if (t == 0) csum[blockIdx.x] = sdata[0];
}

__global__ void k_scan_chunks(const int* __restrict__ csum, int* __restrict__ coff){
    __shared__ int s[512];
    int t = threadIdx.x;
    int v = (t < NCHUNK) ? csum[t] : 0;
    s[t] = v; __syncthreads();
    int x = v;
    for (int off = 1; off < 512; off <<= 1){
        int y = (t >= off) ? s[t-off] : 0;
        __syncthreads();
        x += y; s[t] = x;
        __syncthreads();
    }
    if (t < NCHUNK) coff[t] = x - v;   // exclusive
}

__global__ void k_rowptr(const int* __restrict__ deg, const int* __restrict__ coff,
                         int* __restrict__ row_ptr){
    __shared__ int s[256];
    int t = threadIdx.x, b = blockIdx.x;
    int idx = b*256 + t;
    int v = (idx < NN) ? deg[idx] : 0;
    s[t] = v; __syncthreads();
    int x = v;
    for (int off = 1; off < 256; off <<= 1){
        int y = (t >= off) ? s[t-off] : 0;
        __syncthreads();
        x += y; s[t] = x;
        __syncthreads();
    }
    if (idx < NN)       row_ptr[idx] = coff[b] + x - v;   // exclusive
    if (idx == NN - 1)  row_ptr[NN]  = coff[b] + x;       // total = NE
}

__global__ void k_scatter(const int* __restrict__ src, const int* __restrict__ dst,
                          const int* __restrict__ row_ptr, int* __restrict__ fill,
                          int2* __restrict__ pair_sorted){
    int stride = gridDim.x * blockDim.x;
    for (int i = blockIdx.x*blockDim.x + threadIdx.x; i < NE; i += stride){
        int d = dst[i];
        if ((unsigned)d >= (unsigned)NN) continue;
        int p = row_ptr[d] + atomicAdd(&fill[d], 1);
        if ((unsigned)p < (unsigned)NE){
            int s = src[i];
            if ((unsigned)s >= (unsigned)NN) s = 0;
            pair_sorted[p] = make_int2(s, i);
        }
    }
}

// ---------------- edge-attr reorder into p-sorted order (bf16 packed) ----------------
template<int IS32>
__global__ __launch_bounds__(256) void k_reorder(const int2* __restrict__ pair_sorted,
                                                 const void* __restrict__ ea,
                                                 const int* __restrict__ flg,
                                                 uint4* __restrict__ ea_srt){
    if (flg[0] != IS32) return;
    int stride = gridDim.x * blockDim.x;
    for (int p = blockIdx.x*blockDim.x + threadIdx.x; p < NE; p += stride){
        int eid = pair_sorted[p].y;
        if ((unsigned)eid >= (unsigned)NE) eid = 0;
        uint4 o0, o1;
        if (IS32){
            const float4* er = (const float4*)ea + (size_t)eid*4;
            float4 u0 = er[0], u1 = er[1], u2 = er[2], u3 = er[3];
            o0.x = pack2(u0.x, u0.y); o0.y = pack2(u0.z, u0.w);
            o0.z = pack2(u1.x, u1.y); o0.w = pack2(u1.z, u1.w);
            o1.x = pack2(u2.x, u2.y); o1.y = pack2(u2.z, u2.w);
            o1.z = pack2(u3.x, u3.y); o1.w = pack2(u3.z, u3.w);
        } else {
            const uint4* er = (const uint4*)ea + (size_t)eid*2;
            o0 = er[0]; o1 = er[1];
        }
        ea_srt[(size_t)p*2 + 0] = o0;
        ea_srt[(size_t)p*2 + 1] = o1;
    }
}

// ---------------- input projection: h = x @ src_w + src_b (bf16 out, dword-packed store) ----------------
template<int IS32>
__global__ __launch_bounds__(256) void k_proj(const void* __restrict__ x,
                                              const void* __restrict__ w,
                                              const void* __restrict__ b,
                                              const int* __restrict__ flg,
                                              u16* __restrict__ h){
    if (flg[0] != IS32) return;
    int lane = threadIdx.x & 63;
    int wid  = (blockIdx.x*256 + threadIdx.x) >> 6;
    int nw   = (gridDim.x*256) >> 6;
    float wr[32];
    #pragma unroll
    for (int k = 0; k < 32; k++) wr[k] = ldx<IS32>(w, k*64 + lane);
    float bias = ldx<IS32>(b, lane);
    for (int node = wid; node < NN; node += nw){
        float acc = bias;
        if (IS32){
            const float* xr = (const float*)x + (size_t)node*32;
            #pragma unroll
            for (int k = 0; k < 32; k++) acc = fmaf(xr[k], wr[k], acc);
        } else {
            const u16* xr = (const u16*)x + (size_t)node*32;
            #pragma unroll
            for (int k = 0; k < 32; k++) acc = fmaf(bf16f(xr[k]), wr[k], acc);
        }
        float accn = __shfl_xor(acc, 1, 64);
        if (!(lane & 1))
            ((u32*)h)[(size_t)node*32 + (lane >> 1)] = pack2(acc, accn);
    }
}

// 16-channel dot of one bf16-packed edge-attr row with per-lane ew column
__device__ __forceinline__ float edot(uint4 a, uint4 b, const float* ewr, float ebr){
    float e = ebr;
    e = fmaf(bf_lo(a.x), ewr[0],  e); e = fmaf(bf_hi(a.x), ewr[1],  e);
    e = fmaf(bf_lo(a.y), ewr[2],  e); e = fmaf(bf_hi(a.y), ewr[3],  e);
    e = fmaf(bf_lo(a.z), ewr[4],  e); e = fmaf(bf_hi(a.z), ewr[5],  e);
    e = fmaf(bf_lo(a.w), ewr[6],  e); e = fmaf(bf_hi(a.w), ewr[7],  e);
    e = fmaf(bf_lo(b.x), ewr[8],  e); e = fmaf(bf_hi(b.x), ewr[9],  e);
    e = fmaf(bf_lo(b.y), ewr[10], e); e = fmaf(bf_hi(b.y), ewr[11], e);
    e = fmaf(bf_lo(b.z), ewr[12], e); e = fmaf(bf_hi(b.z), ewr[13], e);
    e = fmaf(bf_lo(b.w), ewr[14], e); e = fmaf(bf_hi(b.w), ewr[15], e);
    return e;
}

// ================= TWO-PASS FAST PATH (chunked to fit workspace) =================
// Chunk c covers nodes [n0,n1), whose edges are the contiguous slot span
// [row_ptr[n0], row_ptr[n1]) because pair_sorted is dst-sorted.
//
// Pass 1 (k_msg): edge-parallel, no serial per-node chain. msg layout is tiled:
//   [tile][lane=channel][4 edges] -> each lane writes/reads a float4 holding ITS
//   channel for 4 consecutive edges. Writes are 1KB-contiguous per tile; pass 2
//   needs NO transpose.
template<int IS32>
__global__ __launch_bounds__(256) void k_msg(
    const u16*   __restrict__ h_in,
    const int*   __restrict__ row_ptr,
    const int2*  __restrict__ pair_sorted,
    const uint4* __restrict__ ea_srt,
    const void* __restrict__ ew, const void* __restrict__ eb,
    const int* __restrict__ flg,
    float4* __restrict__ msg,          // [cap/4][64] float4
    int n0, int n1, int cap)           // cap: multiple of 4
{
    if (flg[0] != IS32) return;
    int lane = threadIdx.x & 63;
    int wid  = (blockIdx.x*256 + threadIdx.x) >> 6;
    int nw   = (gridDim.x*256) >> 6;

    int e0 = row_ptr[n0]; if (e0 < 0) e0 = 0;
    int e1 = row_ptr[n1]; if (e1 > NE) e1 = NE;
    int nq = e1 - e0;
    if (nq <= 0) return;
    if (nq > cap) nq = cap;            // defensive (never on bench input)
    int ntile = (nq + 3) >> 2;

    float ewr[16];
    #pragma unroll
    for (int k = 0; k < 16; k++) ewr[k] = ldx<IS32>(ew, k*64 + lane);
    float ebr = ldx<IS32>(eb, lane);

    for (int tile = wid; tile < ntile; tile += nw){
        int qb = tile << 2;
        // 4 src indices via one cooperative load + shfl
        int sp = 0;
        if (lane < 4){
            int q = qb + lane; if (q >= nq) q = nq - 1;
            sp = pair_sorted[e0 + q].x;
            if ((unsigned)sp >= (unsigned)NN) sp = 0;
        }
        int s0 = __shfl(sp, 0, 64);
        int s1 = __shfl(sp, 1, 64);
        int s2 = __shfl(sp, 2, 64);
        int s3 = __shfl(sp, 3, 64);
        // 4 independent random 128B h-row reads (dword-granular per lane)
        int hw_i = lane >> 1;
        u32 h0 = ((const u32*)h_in)[(size_t)s0*32 + hw_i];
        u32 h1 = ((const u32*)h_in)[(size_t)s1*32 + hw_i];
        u32 h2 = ((const u32*)h_in)[(size_t)s2*32 + hw_i];
        u32 h3 = ((const u32*)h_in)[(size_t)s3*32 + hw_i];
        // 8 broadcast ea reads (sequential in slot order), clamped like sp
        int q0 = qb,     q1 = qb+1 < nq ? qb+1 : nq-1;
        int q2 = qb+2 < nq ? qb+2 : nq-1;
        int q3 = qb+3 < nq ? qb+3 : nq-1;
        uint4 A0 = ea_srt[(size_t)(e0+q0)*2], B0 = ea_srt[(size_t)(e0+q0)*2+1];
        uint4 A1 = ea_srt[(size_t)(e0+q1)*2], B1 = ea_srt[(size_t)(e0+q1)*2+1];
        uint4 A2 = ea_srt[(size_t)(e0+q2)*2], B2 = ea_srt[(size_t)(e0+q2)*2+1];
        uint4 A3 = ea_srt[(size_t)(e0+q3)*2], B3 = ea_srt[(size_t)(e0+q3)*2+1];

        bool odd = (lane & 1);
        float4 v;
        v.x = fmaxf((odd ? bf_hi(h0) : bf_lo(h0)) + edot(A0, B0, ewr, ebr), 0.f) + 1e-7f;
        v.y = fmaxf((odd ? bf_hi(h1) : bf_lo(h1)) + edot(A1, B1, ewr, ebr), 0.f) + 1e-7f;
        v.z = fmaxf((odd ? bf_hi(h2) : bf_lo(h2)) + edot(A2, B2, ewr, ebr), 0.f) + 1e-7f;
        v.w = fmaxf((odd ? bf_hi(h3) : bf_lo(h3)) + edot(A3, B3, ewr, ebr), 0.f) + 1e-7f;

        msg[(size_t)tile*64 + lane] = v;   // 1KB contiguous per tile
    }
}

// Pass 2 (k_sm): node-parallel softmax-reduce + MLP. All msg reads are
// sequential float4s in this lane's channel; no LDS transpose; 32KB LDS.
template<int IS32>
__global__ __launch_bounds__(256, 4) void k_sm(
    const u16*   __restrict__ h_in,
    const int*   __restrict__ row_ptr,
    const float4* __restrict__ msg,
    const void* __restrict__ w1, const void* __restrict__ b1,
    const void* __restrict__ g,  const void* __restrict__ bb,
    const void* __restrict__ w2, const void* __restrict__ b2,
    const int* __restrict__ flg,
    u16* __restrict__ h_out,
    int n0, int n1, int cap)
{
    if (flg[0] != IS32) return;

    __shared__ u32 w1p[64*64];     // 16 KB
    __shared__ u32 w2p[64*64];     // 16 KB

    int t = threadIdx.x;
    for (int i = t; i < 64*64; i += 256){
        int k = i >> 6, c = i & 63;
        u32 lo1, hi1, lo2, hi2;
        if (IS32){
            lo1 = f2bf(((const float*)w1)[k*128 + c]);
            hi1 = f2bf(((const float*)w1)[k*128 + c + 64]);
            lo2 = f2bf(((const float*)w2)[k*64 + c]);
            hi2 = f2bf(((const float*)w2)[(k+64)*64 + c]);
        } else {
            lo1 = ((const u16*)w1)[k*128 + c];
            hi1 = ((const u16*)w1)[k*128 + c + 64];
            lo2 = ((const u16*)w2)[k*64 + c];
            hi2 = ((const u16*)w2)[(k+64)*64 + c];
        }
        w1p[i] = lo1 | (hi1 << 16);
        w2p[i] = lo2 | (hi2 << 16);
    }
    __syncthreads();

    int lane = t & 63;
    int wid = (blockIdx.x*256 + t) >> 6;
    int nw  = (gridDim.x*256) >> 6;

    const float BNS = 0.9999950000374997f;   // 1/sqrt(1+1e-5)
    float b1a = ldx<IS32>(b1, lane), b1b = ldx<IS32>(b1, lane+64);
    float ga  = ldx<IS32>(g, lane)*BNS,  gb  = ldx<IS32>(g, lane+64)*BNS;
    float bba = ldx<IS32>(bb, lane),     bbb = ldx<IS32>(bb, lane+64);
    float b2r = ldx<IS32>(b2, lane);

    int e0 = row_ptr[n0]; if (e0 < 0) e0 = 0;
    int e1g = row_ptr[n1]; if (e1g > NE) e1g = NE;
    int nq = e1g - e0; if (nq > cap) nq = cap; if (nq < 0) nq = 0;

    for (int node = n0 + wid; node < n1; node += nw){
        int q0 = row_ptr[node]   - e0;
        int q1 = row_ptr[node+1] - e0;
        if (q0 < 0) q0 = 0;
        if (q1 > nq) q1 = nq;
        u32 hw_ = ((const u32*)h_in)[(size_t)node*32 + (lane >> 1)];
        float hself = (lane & 1) ? bf_hi(hw_) : bf_lo(hw_);

        float m = -1e30f, sw = 0.f, swm = 0.f;
        if (q1 > q0){
            int t0 = q0 >> 2, t1 = (q1 + 3) >> 2;
            float4 f = msg[(size_t)t0*64 + lane];           // prefetch
            for (int tt = t0; tt < t1; ++tt){
                float4 fc = f;
                if (tt + 1 < t1) f = msg[(size_t)(tt+1)*64 + lane];
                int lo = q0 - (tt<<2); if (lo < 0) lo = 0;
                int hi = q1 - (tt<<2); if (hi > 4) hi = 4;
                float v[4] = {fc.x, fc.y, fc.z, fc.w};
                float vm = -1e30f;
                #pragma unroll
                for (int j = 0; j < 4; j++)
                    if (j >= lo && j < hi) vm = fmaxf(vm, v[j]);
                float nm = fmaxf(m, vm);
                float sc = __expf(m - nm);                  // 0 on first tile
                sw *= sc; swm *= sc;
                #pragma unroll
                for (int j = 0; j < 4; j++){
                    if (j >= lo && j < hi){
                        float pw = __expf(v[j] - nm);
                        sw += pw; swm += pw*v[j];
                    }
                }
                m = nm;
            }
        }
        float agg = (sw > 0.f) ? (swm / sw) : 0.f;
        float out = agg + hself;

        // MLP: 64 -> 128 (BN + relu) -> 64, then outer relu
        float acc1 = b1a, acc2 = b1b;
        #pragma unroll
        for (int k = 0; k < 64; k++){
            float ok = __shfl(out, k, 64);
            u32 wp = w1p[k*64 + lane];
            acc1 = fmaf(ok, bf_lo(wp), acc1);
            acc2 = fmaf(ok, bf_hi(wp), acc2);
        }
        float hh1 = fmaxf(fmaf(acc1, ga, bba), 0.f);
        float hh2 = fmaxf(fmaf(acc2, gb, bbb), 0.f);
        float acc = b2r;
        #pragma unroll
        for (int j = 0; j < 64; j++){
            float a1 = __shfl(hh1, j, 64);
            float a2 = __shfl(hh2, j, 64);
            u32 wp = w2p[j*64 + lane];
            acc = fmaf(a1, bf_lo(wp), acc);
            acc = fmaf(a2, bf_hi(wp), acc);
        }
        float vfin = fmaxf(acc, 0.f);
        float vnext = __shfl_xor(vfin, 1, 64);
        if (!(lane & 1))
            ((u32*)h_out)[(size_t)node*32 + (lane >> 1)] = pack2(vfin, vnext);
    }
}

// ---------------- fused GENConv layer (FALLBACK — identical to round 3) ----------------
template<int IS32>
__global__ __launch_bounds__(256, 4) void k_layer(
    const u16*   __restrict__ h_in,
    const int*   __restrict__ row_ptr,
    const int2*  __restrict__ pair_sorted,
    const uint4* __restrict__ ea_srt,
    const void* __restrict__ ew, const void* __restrict__ eb,
    const void* __restrict__ w1, const void* __restrict__ b1,
    const void* __restrict__ g,  const void* __restrict__ bb,
    const void* __restrict__ w2, const void* __restrict__ b2,
    const int* __restrict__ flg,
    u16* __restrict__ h_out)
{
    if (flg[0] != IS32) return;

    __shared__ u32 w1p[64*64];
    __shared__ u32 w2p[64*64];
    __shared__ u32 tbuf[4*2*256];

    int t = threadIdx.x;
    for (int i = t; i < 64*64; i += 256){
        int k = i >> 6, c = i & 63;
        u32 lo1, hi1, lo2, hi2;
        if (IS32){
            lo1 = f2bf(((const float*)w1)[k*128 + c]);
            hi1 = f2bf(((const float*)w1)[k*128 + c + 64]);
            lo2 = f2bf(((const float*)w2)[k*64 + c]);
            hi2 = f2bf(((const float*)w2)[(k+64)*64 + c]);
        } else {
            lo1 = ((const u16*)w1)[k*128 + c];
            hi1 = ((const u16*)w1)[k*128 + c + 64];
            lo2 = ((const u16*)w2)[k*64 + c];
            hi2 = ((const u16*)w2)[(k+64)*64 + c];
        }
        w1p[i] = lo1 | (hi1 << 16);
        w2p[i] = lo2 | (hi2 << 16);
    }
    __syncthreads();

    int lane = t & 63;
    int wslot = t >> 6;
    u32* tb0 = &tbuf[wslot*512];
    int wid  = (blockIdx.x*256 + t) >> 6;
    int nw   = (gridDim.x*256) >> 6;

    float ewr[16];
    #pragma unroll
    for (int k = 0; k < 16; k++) ewr[k] = ldx<IS32>(ew, k*64 + lane);
    float ebr = ldx<IS32>(eb, lane);
    const float BNS = 0.9999950000374997f;
    float b1a = ldx<IS32>(b1, lane), b1b = ldx<IS32>(b1, lane+64);
    float ga  = ldx<IS32>(g, lane)*BNS,  gb  = ldx<IS32>(g, lane+64)*BNS;
    float bba = ldx<IS32>(bb, lane),     bbb = ldx<IS32>(bb, lane+64);
    float b2r = ldx<IS32>(b2, lane);

    int elane = lane >> 3;
    int eq    = lane & 7;

    for (int node = wid; node < NN; node += nw){
        int p0 = row_ptr[node], p1 = row_ptr[node+1];
        if (p0 < 0) p0 = 0;
        if (p1 > NE) p1 = NE;
        u32 hw_ = ((const u32*)h_in)[(size_t)node*32 + (lane >> 1)];
        float hself = (lane & 1) ? bf_hi(hw_) : bf_lo(hw_);

        float m = -1e30f, sw = 0.f, swm = 0.f;

        for (int base = p0; base < p1; base += 64){
            int nch = p1 - base; if (nch > 64) nch = 64;
            int sidx = 0;
            if (lane < nch) sidx = pair_sorted[base + lane].x;

            int ngr = (nch + 7) >> 3;
            int slot0 = elane; if (slot0 >= nch) slot0 = nch - 1;
            int s_g   = __shfl(sidx, slot0, 64);
            uint4 hv  = ((const uint4*)h_in)[(size_t)s_g*8 + eq];

            for (int gidx = 0; gidx < ngr; ++gidx){
                uint4 hvn = hv;
                if (gidx + 1 < ngr){
                    int sl = (gidx+1)*8 + elane; if (sl >= nch) sl = nch - 1;
                    int sn = __shfl(sidx, sl, 64);
                    hvn = ((const uint4*)h_in)[(size_t)sn*8 + eq];
                }
                u32* lb = tb0 + ((gidx & 1) << 8);
                ((uint4*)lb)[lane] = hv;
                float hr[8];
                #pragma unroll
                for (int e = 0; e < 8; e++){
                    u32 w = lb[e*32 + (lane >> 1)];
                    hr[e] = (lane & 1) ? bf_hi(w) : bf_lo(w);
                }

                #pragma unroll
                for (int sub = 0; sub < 2; ++sub){
                    int sbase = gidx*8 + sub*4;
                    int nv = nch - sbase;
                    if (nv > 0){
                        if (nv > 4) nv = 4;
                        int l0 = sbase;
                        int l1 = l0 + (nv > 1);
                        int l2 = l1 + (nv > 2);
                        int l3 = l2 + (nv > 3);
                        uint4 A0 = ea_srt[(size_t)(base+l0)*2], B0 = ea_srt[(size_t)(base+l0)*2+1];
                        uint4 A1 = ea_srt[(size_t)(base+l1)*2], B1 = ea_srt[(size_t)(base+l1)*2+1];
                        uint4 A2 = ea_srt[(size_t)(base+l2)*2], B2 = ea_srt[(size_t)(base+l2)*2+1];
                        uint4 A3 = ea_srt[(size_t)(base+l3)*2], B3 = ea_srt[(size_t)(base+l3)*2+1];

                        float v0 = fmaxf(hr[sub*4+0] + edot(A0, B0, ewr, ebr), 0.f) + 1e-7f;
                        float v1 = fmaxf(hr[sub*4+1] + edot(A1, B1, ewr, ebr), 0.f) + 1e-7f;
                        float v2 = fmaxf(hr[sub*4+2] + edot(A2, B2, ewr, ebr), 0.f) + 1e-7f;
                        float v3 = fmaxf(hr[sub*4+3] + edot(A3, B3, ewr, ebr), 0.f) + 1e-7f;

                        float vm = v0;
                        if (nv > 1) vm = fmaxf(vm, v1);
                        if (nv > 2) vm = fmaxf(vm, v2);
                        if (nv > 3) vm = fmaxf(vm, v3);
                        float nm = fmaxf(m, vm);
                        float sc = __expf(m - nm);
                        sw *= sc; swm *= sc;
                        float pw;
                        pw = __expf(v0 - nm); sw += pw; swm += pw*v0;
                        if (nv > 1){ pw = __expf(v1 - nm); sw += pw; swm += pw*v1; }
                        if (nv > 2){ pw = __expf(v2 - nm); sw += pw; swm += pw*v2; }
                        if (nv > 3){ pw = __expf(v3 - nm); sw += pw; swm += pw*v3; }
                        m = nm;
                    }
                }
                hv = hvn;
            }
        }
        float agg = (sw > 0.f) ? (swm / sw) : 0.f;
        float out = agg + hself;

        float acc1 = b1a, acc2 = b1b;
        #pragma unroll
        for (int k = 0; k < 64; k++){
            float ok = __shfl(out, k, 64);
            u32 wp = w1p[k*64 + lane];
            acc1 = fmaf(ok, bf_lo(wp), acc1);
            acc2 = fmaf(ok, bf_hi(wp), acc2);
        }
        float hh1 = fmaxf(fmaf(acc1, ga, bba), 0.f);
        float hh2 = fmaxf(fmaf(acc2, gb, bbb), 0.f);
        float acc = b2r;
        #pragma unroll
        for (int j = 0; j < 64; j++){
            float a1 = __shfl(hh1, j, 64);
            float a2 = __shfl(hh2, j, 64);
            u32 wp = w2p[j*64 + lane];
            acc = fmaf(a1, bf_lo(wp), acc);
            acc = fmaf(a2, bf_hi(wp), acc);
        }
        float vfin = fmaxf(acc, 0.f);
        float vnext = __shfl_xor(vfin, 1, 64);
        if (!(lane & 1))
            ((u32*)h_out)[(size_t)node*32 + (lane >> 1)] = pack2(vfin, vnext);
    }
}

// ---------------- head: out = concat(h, gf) @ head_w + head_b  (FP32 OUT) ----------------
template<int IS32>
__global__ __launch_bounds__(256) void k_head(const u16* __restrict__ h,
                                              const void* __restrict__ gf,
                                              const int* __restrict__ ngp,
                                              const void* __restrict__ hw,
                                              const void* __restrict__ hb,
                                              const int* __restrict__ flg,
                                              float* __restrict__ out){
    if (flg[0] != IS32) return;
    int lane = threadIdx.x & 63;
    int wid  = (blockIdx.x*256 + threadIdx.x) >> 6;
    int nw   = (gridDim.x*256) >> 6;
    int dw = lane & 31;
    bool active = lane < 32;
    float wc0 = active ? ldx<IS32>(hw, 2*dw)     : 0.f;
    float wc1 = active ? ldx<IS32>(hw, 2*dw + 1) : 0.f;
    float w64 = ldx<IS32>(hw, 64), w65 = ldx<IS32>(hw, 65);
    float bias = ldx<IS32>(hb, 0);
    int ng  = ngp[0];
    if (ng <= 0) ng = 1;
    int npg = NN / ng;
    if (npg <= 0) npg = 1;
    for (int node = wid; node < NN; node += nw){
        float v = 0.f;
        if (active){
            u32 w = ((const u32*)h)[(size_t)node*32 + dw];
            v = bf_lo(w)*wc0 + bf_hi(w)*wc1;
        }
        #pragma unroll
        for (int off = 32; off > 0; off >>= 1) v += __shfl_xor(v, off, 64);
        if (lane == 0){
            int gidx = node / npg, r = node - gidx*npg;
            float g0 = ldx<IS32>(gf, (gidx*2 + 0)*npg + r);
            float g1 = ldx<IS32>(gf, (gidx*2 + 1)*npg + r);
            out[node] = v + g0*w64 + g1*w65 + bias;
        }
    }
}

// ---------------- launch ----------------
extern "C" void kernel_launch(void* const* d_in, const int* in_sizes, int n_in,
                              void* d_out, int out_size, void* d_ws, size_t ws_size,
                              hipStream_t stream){
    const void* x    = d_in[0];
    const int*  ei   = (const int*)d_in[1];          // [2, NE]: row0=src, row1=dst
    const void* ea   = d_in[2];
    const int*  ngp  = (const int*)d_in[3];
    const void* gf   = d_in[4];
    const void* srcw = d_in[5];
    const void* srcb = d_in[6];
    const void* L[16];
    for (int i = 0; i < 16; i++) L[i] = d_in[7 + i];
    const void* headw = d_in[23];
    const void* headb = d_in[24];

    char* ws = (char*)d_ws;
    size_t off = 0;
    auto alloc = [&](size_t bytes) -> void* {
        void* p = ws + off;
        off += (bytes + 255) & ~size_t(255);
        return p;
    };
    u16* hA          = (u16*)  alloc((size_t)NN*64*2);    // 12.8 MB
    u16* hB          = (u16*)  alloc((size_t)NN*64*2);    // 12.8 MB
    int* row_ptr     = (int*)  alloc((size_t)(NN+1)*4);
    int* cnt         = (int*)  alloc((size_t)2*NN*4);     // deg | fill
    int* deg  = cnt;
    int* fill = cnt + NN;
    int* csum        = (int*)  alloc((size_t)NCHUNK*4);
    int* coff        = (int*)  alloc((size_t)NCHUNK*4);
    int* flg         = (int*)  alloc(256);
    int2* pair_sorted= (int2*) alloc((size_t)NE*8);       // 12.8 MB
    uint4* ea_srt    = (uint4*)alloc((size_t)NE*32);      // 51.2 MB
    // adaptive msg chunking: pick smallest #chunks whose buffer fits the workspace
    size_t avail = (ws_size > off) ? (ws_size - off) : 0;
    int nch = 0; long cap = 0;
    {
        const int cands[5] = {1, 2, 4, 8, 16};
        for (int ci = 0; ci < 5; ci++){
            int c = cands[ci];
            long need = (c == 1) ? (long)NE
                                 : (long)((double)NE / c * 1.2) + 4096;
            need = (need + 3) & ~3L;                      // multiple of 4
            if ((size_t)need * 256 + (1u<<20) <= avail){ nch = c; cap = need; break; }
        }
    }
    float4* msgbuf = nch ? (float4*)alloc((size_t)cap * 256) : nullptr;

    hipMemsetAsync(cnt, 0, (size_t)2*NN*4, stream);

    const int* e_src = ei;
    const int* e_dst = ei + NE;

    k_sniff      <<<1, 256, 0, stream>>>((const u32*)x, flg);
    k_deg        <<<1024, 256, 0, stream>>>(e_dst, deg);
    k_csum       <<<NCHUNK, 256, 0, stream>>>(deg, csum);
    k_scan_chunks<<<1, 512, 0, stream>>>(csum, coff);
    k_rowptr     <<<NCHUNK, 256, 0, stream>>>(deg, coff, row_ptr);
    k_scatter    <<<1024, 256, 0, stream>>>(e_src, e_dst, row_ptr, fill, pair_sorted);

    k_reorder<1> <<<2048, 256, 0, stream>>>(pair_sorted, ea, flg, ea_srt);
    k_reorder<0> <<<2048, 256, 0, stream>>>(pair_sorted, ea, flg, ea_srt);

    k_proj<1>    <<<512, 256, 0, stream>>>(x, srcw, srcb, flg, hA);
    k_proj<0>    <<<512, 256, 0, stream>>>(x, srcw, srcb, flg, hA);

    if (nch){
        int nc = (NN + nch - 1) / nch;
        for (int layer = 0; layer < 2; layer++){
            const u16* hin  = layer ? hB : hA;
            u16*       hout = layer ? hA : hB;
            const void* ewp = L[layer*8 + 0], *ebp = L[layer*8 + 1];
            const void* w1p = L[layer*8 + 2], *b1p = L[layer*8 + 3];
            const void* gp  = L[layer*8 + 4], *bbp = L[layer*8 + 5];
            const void* w2p = L[layer*8 + 6], *b2p = L[layer*8 + 7];
            for (int c = 0; c < nch; c++){
                int n0 = c * nc;
                int n1 = n0 + nc; if (n1 > NN) n1 = NN;
                if (n0 >= n1) break;
                k_msg<1> <<<4096, 256, 0, stream>>>(hin, row_ptr, pair_sorted, ea_srt,
                                ewp, ebp, flg, msgbuf, n0, n1, (int)cap);
                k_msg<0> <<<4096, 256, 0, stream>>>(hin, row_ptr, pair_sorted, ea_srt,
                                ewp, ebp, flg, msgbuf, n0, n1, (int)cap);
                k_sm<1>  <<<1024, 256, 0, stream>>>(hin, row_ptr, msgbuf,
                                w1p, b1p, gp, bbp, w2p, b2p, flg, hout, n0, n1, (int)cap);
                k_sm<0>  <<<1024, 256, 0, stream>>>(hin, row_ptr, msgbuf,
                                w1p, b1p, gp, bbp, w2p, b2p, flg, hout, n0, n1, (int)cap);
            }
        }
    } else {
        k_layer<1> <<<1024, 256, 0, stream>>>(hA, row_ptr, pair_sorted, ea_srt,
                        L[0], L[1], L[2], L[3], L[4], L[5], L[6], L[7], flg, hB);
        k_layer<0> <<<1024, 256, 0, stream>>>(hA, row_ptr, pair_sorted, ea_srt,
                        L[0], L[1], L[2], L[3], L[4], L[5], L[6], L[7], flg, hB);
        k_layer<1> <<<1024, 256, 0, stream>>>(hB, row_ptr, pair_sorted, ea_srt,
                        L[8], L[9], L[10], L[11], L[12], L[13], L[14], L[15], flg, hA);
        k_layer<0> <<<1024, 256, 0, stream>>>(hB, row_ptr, pair_sorted, ea_srt,
                        L[8], L[9], L[10], L[11], L[12], L[13], L[14], L[15], flg, hA);
    }

    k_head<1>    <<<512, 256, 0, stream>>>(hA, gf, ngp, headw, headb, flg, (float*)d_out);
    k_head<0>    <<<512, 256, 0, stream>>>(hA, gf, ngp, headw, headb, flg, (float*)d_out);
}

// Round 7
// 2809.128 us; speedup vs baseline: 2.9083x; 1.7198x over previous
//
#include <hip/hip_runtime.h>
#include <hip/hip_bf16.h>
#include <hip/hip_fp16.h>

#define NN 100000
#define NE 1600000
#define NCHUNK 391   // ceil(100000/256)

typedef unsigned short u16;
typedef unsigned int   u32;

__device__ __forceinline__ float bfu(u32 v){ union{u32 i; float f;} w; w.i = v<<16; return w.f; }
__device__ __forceinline__ float bf_lo(u32 u){ return bfu(u & 0xffffu); }
__device__ __forceinline__ float bf_hi(u32 u){ return bfu(u >> 16); }
__device__ __forceinline__ float bf16f(u16 u){ return bfu((u32)u); }
__device__ __forceinline__ u16 f2bf(float f){
    union{float f; u32 i;} w; w.f = f;
    u32 r = (w.i + 0x7fffu + ((w.i >> 16) & 1u)) >> 16;   // RNE
    return (u16)r;
}
__device__ __forceinline__ u32 pack2(float lo, float hi){
    return (u32)f2bf(lo) | ((u32)f2bf(hi) << 16);
}
__device__ __forceinline__ u16 f2h(float f){ return __half_as_ushort(__float2half(f)); }
__device__ __forceinline__ float h2f(u16 u){ return __half2float(__ushort_as_half(u)); }

template<int IS32>
__device__ __forceinline__ float ldx(const void* p, int i){
    if (IS32) return ((const float*)p)[i];
    else      return bf16f(((const u16*)p)[i]);
}

// ---------------- dtype sniff: fp32 (1) vs bf16 (0) ----------------
__global__ void k_sniff(const u32* __restrict__ x, int* __restrict__ flag){
    __shared__ int cnt[256];
    int t = threadIdx.x;
    int bad = 0;
    for (int i = t; i < 512; i += 256){
        u32 w = x[i];
        u32 lo = w & 0xffffu;
        u32 e = (lo >> 7) & 0xffu;
        bool sane = (lo == 0u) || (lo == 0x8000u) || (e >= 85u && e <= 133u);
        if (!sane) bad++;
    }
    cnt[t] = bad; __syncthreads();
    for (int s = 128; s > 0; s >>= 1){
        if (t < s) cnt[t] += cnt[t+s];
        __syncthreads();
    }
    if (t == 0) flag[0] = (cnt[0] > 100) ? 1 : 0;
}

// ---------------- CSR build (dtype-independent) ----------------

__global__ void k_deg(const int* __restrict__ dst, int* __restrict__ deg){
    int stride = gridDim.x * blockDim.x;
    for (int i = blockIdx.x*blockDim.x + threadIdx.x; i < NE; i += stride){
        int d = dst[i];
        if ((unsigned)d < (unsigned)NN) atomicAdd(&deg[d], 1);
    }
}

__global__ void k_csum(const int* __restrict__ deg, int* __restrict__ csum){
    __shared__ int sdata[256];
    int t = threadIdx.x;
    int idx = blockIdx.x*256 + t;
    sdata[t] = (idx < NN) ? deg[idx] : 0;
    __syncthreads();
    for (int s = 128; s > 0; s >>= 1){
        if (t < s) sdata[t] += sdata[t+s];
        __syncthreads();
    }
    if (t == 0) csum[blockIdx.x] = sdata[0];
}

__global__ void k_scan_chunks(const int* __restrict__ csum, int* __restrict__ coff){
    __shared__ int s[512];
    int t = threadIdx.x;
    int v = (t < NCHUNK) ? csum[t] : 0;
    s[t] = v; __syncthreads();
    int x = v;
    for (int off = 1; off < 512; off <<= 1){
        int y = (t >= off) ? s[t-off] : 0;
        __syncthreads();
        x += y; s[t] = x;
        __syncthreads();
    }
    if (t < NCHUNK) coff[t] = x - v;   // exclusive
}

__global__ void k_rowptr(const int* __restrict__ deg, const int* __restrict__ coff,
                         int* __restrict__ row_ptr){
    __shared__ int s[256];
    int t = threadIdx.x, b = blockIdx.x;
    int idx = b*256 + t;
    int v = (idx < NN) ? deg[idx] : 0;
    s[t] = v; __syncthreads();
    int x = v;
    for (int off = 1; off < 256; off <<= 1){
        int y = (t >= off) ? s[t-off] : 0;
        __syncthreads();
        x += y; s[t] = x;
        __syncthreads();
    }
    if (idx < NN)       row_ptr[idx] = coff[b] + x - v;   // exclusive
    if (idx == NN - 1)  row_ptr[NN]  = coff[b] + x;       // total = NE
}

__global__ void k_scatter(const int* __restrict__ src, const int* __restrict__ dst,
                          const int* __restrict__ row_ptr, int* __restrict__ fill,
                          int2* __restrict__ pair_sorted){
    int stride = gridDim.x * blockDim.x;
    for (int i = blockIdx.x*blockDim.x + threadIdx.x; i < NE; i += stride){
        int d = dst[i];
        if ((unsigned)d >= (unsigned)NN) continue;
        int p = row_ptr[d] + atomicAdd(&fill[d], 1);
        if ((unsigned)p < (unsigned)NE){
            int s = src[i];
            if ((unsigned)s >= (unsigned)NN) s = 0;
            pair_sorted[p] = make_int2(s, i);
        }
    }
}

// ---------------- edge-attr reorder into p-sorted order (bf16 packed) ----------------
template<int IS32>
__global__ __launch_bounds__(256) void k_reorder(const int2* __restrict__ pair_sorted,
                                                 const void* __restrict__ ea,
                                                 const int* __restrict__ flg,
                                                 uint4* __restrict__ ea_srt){
    if (flg[0] != IS32) return;
    int stride = gridDim.x * blockDim.x;
    for (int p = blockIdx.x*blockDim.x + threadIdx.x; p < NE; p += stride){
        int eid = pair_sorted[p].y;
        if ((unsigned)eid >= (unsigned)NE) eid = 0;
        uint4 o0, o1;
        if (IS32){
            const float4* er = (const float4*)ea + (size_t)eid*4;
            float4 u0 = er[0], u1 = er[1], u2 = er[2], u3 = er[3];
            o0.x = pack2(u0.x, u0.y); o0.y = pack2(u0.z, u0.w);
            o0.z = pack2(u1.x, u1.y); o0.w = pack2(u1.z, u1.w);
            o1.x = pack2(u2.x, u2.y); o1.y = pack2(u2.z, u2.w);
            o1.z = pack2(u3.x, u3.y); o1.w = pack2(u3.z, u3.w);
        } else {
            const uint4* er = (const uint4*)ea + (size_t)eid*2;
            o0 = er[0]; o1 = er[1];
        }
        ea_srt[(size_t)p*2 + 0] = o0;
        ea_srt[(size_t)p*2 + 1] = o1;
    }
}

// ---------------- input projection ----------------
template<int IS32>
__global__ __launch_bounds__(256) void k_proj(const void* __restrict__ x,
                                              const void* __restrict__ w,
                                              const void* __restrict__ b,
                                              const int* __restrict__ flg,
                                              u16* __restrict__ h){
    if (flg[0] != IS32) return;
    int lane = threadIdx.x & 63;
    int wid  = (blockIdx.x*256 + threadIdx.x) >> 6;
    int nw   = (gridDim.x*256) >> 6;
    float wr[32];
    #pragma unroll
    for (int k = 0; k < 32; k++) wr[k] = ldx<IS32>(w, k*64 + lane);
    float bias = ldx<IS32>(b, lane);
    for (int node = wid; node < NN; node += nw){
        float acc = bias;
        if (IS32){
            const float* xr = (const float*)x + (size_t)node*32;
            #pragma unroll
            for (int k = 0; k < 32; k++) acc = fmaf(xr[k], wr[k], acc);
        } else {
            const u16* xr = (const u16*)x + (size_t)node*32;
            #pragma unroll
            for (int k = 0; k < 32; k++) acc = fmaf(bf16f(xr[k]), wr[k], acc);
        }
        float accn = __shfl_xor(acc, 1, 64);
        if (!(lane & 1))
            ((u32*)h)[(size_t)node*32 + (lane >> 1)] = pack2(acc, accn);
    }
}

// 16-channel dot of one bf16-packed edge-attr row with per-lane ew column
__device__ __forceinline__ float edot(uint4 a, uint4 b, const float* ewr, float ebr){
    float e = ebr;
    e = fmaf(bf_lo(a.x), ewr[0],  e); e = fmaf(bf_hi(a.x), ewr[1],  e);
    e = fmaf(bf_lo(a.y), ewr[2],  e); e = fmaf(bf_hi(a.y), ewr[3],  e);
    e = fmaf(bf_lo(a.z), ewr[4],  e); e = fmaf(bf_hi(a.z), ewr[5],  e);
    e = fmaf(bf_lo(a.w), ewr[6],  e); e = fmaf(bf_hi(a.w), ewr[7],  e);
    e = fmaf(bf_lo(b.x), ewr[8],  e); e = fmaf(bf_hi(b.x), ewr[9],  e);
    e = fmaf(bf_lo(b.y), ewr[10], e); e = fmaf(bf_hi(b.y), ewr[11], e);
    e = fmaf(bf_lo(b.z), ewr[12], e); e = fmaf(bf_hi(b.z), ewr[13], e);
    e = fmaf(bf_lo(b.w), ewr[14], e); e = fmaf(bf_hi(b.w), ewr[15], e);
    return e;
}

// ================= TWO-PASS FAST PATH (fp16 msg, 8 edges/tile, chunked) =================
// Pass 1: edge-parallel message build. Per tile of 8 edges, each lane produces a
// uint4 = 8 fp16 values = ITS channel for 8 consecutive edges -> 1KB contiguous
// store per tile, read back with NO transpose. fp16 rel err 2^-11 (well below the
// bf16-h error floor). Contiguous tile span per wave -> sequential pair/ea/msg.
template<int IS32>
__global__ __launch_bounds__(256, 3) void k_msg(
    const u16*   __restrict__ h_in,
    const int*   __restrict__ row_ptr,
    const int2*  __restrict__ pair_sorted,
    const uint4* __restrict__ ea_srt,
    const void* __restrict__ ew, const void* __restrict__ eb,
    const int* __restrict__ flg,
    uint4* __restrict__ msg,           // [ntile][64] uint4
    int n0, int n1, int cap)           // cap: edge capacity, multiple of 8
{
    if (flg[0] != IS32) return;
    int lane = threadIdx.x & 63;
    int wid  = (blockIdx.x*256 + threadIdx.x) >> 6;
    int nw   = (gridDim.x*256) >> 6;

    int e0 = row_ptr[n0]; if (e0 < 0) e0 = 0;
    int e1 = row_ptr[n1]; if (e1 > NE) e1 = NE;
    int nq = e1 - e0;
    if (nq <= 0) return;
    if (nq > cap) nq = cap;
    int ntile = (nq + 7) >> 3;

    float ewr[16];
    #pragma unroll
    for (int k = 0; k < 16; k++) ewr[k] = ldx<IS32>(ew, k*64 + lane);
    float ebr = ldx<IS32>(eb, lane);

    int per = (ntile + nw - 1) / nw;
    int t0 = wid * per;
    int t1 = t0 + per; if (t1 > ntile) t1 = ntile;
    bool odd = (lane & 1);
    int hw_i = lane >> 1;

    for (int tile = t0; tile < t1; ++tile){
        int qb = tile << 3;
        // 8 src ids: lanes 0..7 load (one 64B line), then broadcast
        int sp = 0;
        if (lane < 8){
            int q = qb + lane; if (q >= nq) q = nq - 1;
            sp = pair_sorted[e0 + q].x;
            if ((unsigned)sp >= (unsigned)NN) sp = 0;
        }
        int se[8];
        #pragma unroll
        for (int e = 0; e < 8; e++) se[e] = __shfl(sp, e, 64);
        // 8 independent random 128B h-row reads
        u32 hr[8];
        #pragma unroll
        for (int e = 0; e < 8; e++)
            hr[e] = ((const u32*)h_in)[(size_t)se[e]*32 + hw_i];
        // 8x 32B sequential broadcast ea reads + edot
        float v[8];
        #pragma unroll
        for (int e = 0; e < 8; e++){
            int q = qb + e; if (q >= nq) q = nq - 1;
            uint4 A = ea_srt[(size_t)(e0+q)*2];
            uint4 B = ea_srt[(size_t)(e0+q)*2 + 1];
            float hs = odd ? bf_hi(hr[e]) : bf_lo(hr[e]);
            v[e] = fmaxf(hs + edot(A, B, ewr, ebr), 0.f) + 1e-7f;
        }
        uint4 o;
        o.x = (u32)f2h(v[0]) | ((u32)f2h(v[1]) << 16);
        o.y = (u32)f2h(v[2]) | ((u32)f2h(v[3]) << 16);
        o.z = (u32)f2h(v[4]) | ((u32)f2h(v[5]) << 16);
        o.w = (u32)f2h(v[6]) | ((u32)f2h(v[7]) << 16);
        msg[(size_t)tile*64 + lane] = o;   // 1KB contiguous per tile
    }
}

// Pass 2: node-parallel softmax-reduce + MLP. Contiguous node range per wave;
// 4-node batches; dense 512B full-wave output store via tiny per-wave LDS
// transpose; 4 interleaved MLP chains for shfl ILP.
template<int IS32>
__global__ __launch_bounds__(256, 4) void k_sm(
    const u16*   __restrict__ h_in,
    const int*   __restrict__ row_ptr,
    const uint4* __restrict__ msg,
    const void* __restrict__ w1, const void* __restrict__ b1,
    const void* __restrict__ g,  const void* __restrict__ bb,
    const void* __restrict__ w2, const void* __restrict__ b2,
    const int* __restrict__ flg,
    u16* __restrict__ h_out,
    int n0, int n1, int cap)
{
    if (flg[0] != IS32) return;

    __shared__ u32 w1p[64*64];       // 16 KB
    __shared__ u32 w2p[64*64];       // 16 KB
    __shared__ u16 sbuf[4][4*64];    // per-wave 512B transpose scratch

    int t = threadIdx.x;
    for (int i = t; i < 64*64; i += 256){
        int k = i >> 6, c = i & 63;
        u32 lo1, hi1, lo2, hi2;
        if (IS32){
            lo1 = f2bf(((const float*)w1)[k*128 + c]);
            hi1 = f2bf(((const float*)w1)[k*128 + c + 64]);
            lo2 = f2bf(((const float*)w2)[k*64 + c]);
            hi2 = f2bf(((const float*)w2)[(k+64)*64 + c]);
        } else {
            lo1 = ((const u16*)w1)[k*128 + c];
            hi1 = ((const u16*)w1)[k*128 + c + 64];
            lo2 = ((const u16*)w2)[k*64 + c];
            hi2 = ((const u16*)w2)[(k+64)*64 + c];
        }
        w1p[i] = lo1 | (hi1 << 16);
        w2p[i] = lo2 | (hi2 << 16);
    }
    __syncthreads();

    int lane  = t & 63;
    int wslot = t >> 6;
    u16* sb   = sbuf[wslot];

    const float BNS = 0.9999950000374997f;   // 1/sqrt(1+1e-5)
    float b1a = ldx<IS32>(b1, lane), b1b = ldx<IS32>(b1, lane+64);
    float ga  = ldx<IS32>(g, lane)*BNS,  gb  = ldx<IS32>(g, lane+64)*BNS;
    float bba = ldx<IS32>(bb, lane),     bbb = ldx<IS32>(bb, lane+64);
    float b2r = ldx<IS32>(b2, lane);

    int e0 = row_ptr[n0]; if (e0 < 0) e0 = 0;
    int e1g = row_ptr[n1]; if (e1g > NE) e1g = NE;
    int nq = e1g - e0; if (nq > cap) nq = cap; if (nq < 0) nq = 0;

    // contiguous node sub-range for this wave
    int nch_nodes = n1 - n0;
    int npb  = (nch_nodes + gridDim.x - 1) / gridDim.x;
    int bn0  = n0 + blockIdx.x * npb;
    int bn1  = bn0 + npb; if (bn1 > n1) bn1 = n1;
    int wnpb = (npb + 3) >> 2;
    int wn0  = bn0 + wslot * wnpb;
    int wn1  = wn0 + wnpb; if (wn1 > bn1) wn1 = bn1;

    for (int nb = wn0; nb < wn1; nb += 4){
        int cntn = wn1 - nb; if (cntn > 4) cntn = 4;
        float outv[4];

        for (int j = 0; j < 4; ++j){
            if (j >= cntn){ outv[j] = 0.f; continue; }
            int node = nb + j;
            int q0 = row_ptr[node]   - e0;
            int q1 = row_ptr[node+1] - e0;
            if (q0 < 0) q0 = 0;
            if (q1 > nq) q1 = nq;
            u32 hw_ = ((const u32*)h_in)[(size_t)node*32 + (lane >> 1)];
            float hself = (lane & 1) ? bf_hi(hw_) : bf_lo(hw_);

            float m = -1e30f, sw = 0.f, swm = 0.f;
            if (q1 > q0){
                int t0n = q0 >> 3, t1n = (q1 + 7) >> 3;
                uint4 f = msg[(size_t)t0n*64 + lane];        // prefetch
                for (int tt = t0n; tt < t1n; ++tt){
                    uint4 fc = f;
                    if (tt + 1 < t1n) f = msg[(size_t)(tt+1)*64 + lane];
                    int lo = q0 - (tt<<3); if (lo < 0) lo = 0;
                    int hi = q1 - (tt<<3); if (hi > 8) hi = 8;
                    float v[8];
                    v[0] = h2f((u16)(fc.x & 0xffffu)); v[1] = h2f((u16)(fc.x >> 16));
                    v[2] = h2f((u16)(fc.y & 0xffffu)); v[3] = h2f((u16)(fc.y >> 16));
                    v[4] = h2f((u16)(fc.z & 0xffffu)); v[5] = h2f((u16)(fc.z >> 16));
                    v[6] = h2f((u16)(fc.w & 0xffffu)); v[7] = h2f((u16)(fc.w >> 16));
                    float vm = -1e30f;
                    #pragma unroll
                    for (int q = 0; q < 8; q++)
                        if (q >= lo && q < hi) vm = fmaxf(vm, v[q]);
                    float nm = fmaxf(m, vm);
                    float sc = __expf(m - nm);               // 0 on first tile
                    sw *= sc; swm *= sc;
                    #pragma unroll
                    for (int q = 0; q < 8; q++){
                        if (q >= lo && q < hi){
                            float pw = __expf(v[q] - nm);
                            sw += pw; swm += pw*v[q];
                        }
                    }
                    m = nm;
                }
            }
            float agg = (sw > 0.f) ? (swm / sw) : 0.f;
            outv[j] = agg + hself;
        }

        // batched MLP: 4 interleaved chains (shfl ILP)
        float acc1[4], acc2[4];
        #pragma unroll
        for (int j = 0; j < 4; j++){ acc1[j] = b1a; acc2[j] = b1b; }
        #pragma unroll
        for (int k = 0; k < 64; k++){
            u32 wp = w1p[k*64 + lane];
            float wl = bf_lo(wp), wh = bf_hi(wp);
            #pragma unroll
            for (int j = 0; j < 4; j++){
                float ok = __shfl(outv[j], k, 64);
                acc1[j] = fmaf(ok, wl, acc1[j]);
                acc2[j] = fmaf(ok, wh, acc2[j]);
            }
        }
        float hh1[4], hh2[4], acc[4];
        #pragma unroll
        for (int j = 0; j < 4; j++){
            hh1[j] = fmaxf(fmaf(acc1[j], ga, bba), 0.f);
            hh2[j] = fmaxf(fmaf(acc2[j], gb, bbb), 0.f);
            acc[j] = b2r;
        }
        #pragma unroll
        for (int k = 0; k < 64; k++){
            u32 wp = w2p[k*64 + lane];
            float wl = bf_lo(wp), wh = bf_hi(wp);
            #pragma unroll
            for (int j = 0; j < 4; j++){
                float a1 = __shfl(hh1[j], k, 64);
                float a2 = __shfl(hh2[j], k, 64);
                acc[j] = fmaf(a1, wl, acc[j]);
                acc[j] = fmaf(a2, wh, acc[j]);
            }
        }

        if (cntn == 4){
            // dense full-wave store: LDS transpose 4x[64]u16 -> uint2 per lane (512B)
            #pragma unroll
            for (int j = 0; j < 4; j++)
                sb[j*64 + lane] = f2bf(fmaxf(acc[j], 0.f));
            // wave-private LDS; compiler inserts lgkmcnt before dependent read
            uint2 ov = ((const uint2*)sb)[lane];
            ((uint2*)(h_out + (size_t)nb*64))[lane] = ov;
        } else {
            for (int j = 0; j < cntn; j++){
                float vfin = fmaxf(acc[j], 0.f);
                float vnext = __shfl_xor(vfin, 1, 64);
                if (!(lane & 1))
                    ((u32*)h_out)[(size_t)(nb+j)*32 + (lane >> 1)] = pack2(vfin, vnext);
            }
        }
    }
}

// ---------------- fused GENConv layer (FALLBACK — tiny workspace only) ----------------
template<int IS32>
__global__ __launch_bounds__(256, 4) void k_layer(
    const u16*   __restrict__ h_in,
    const int*   __restrict__ row_ptr,
    const int2*  __restrict__ pair_sorted,
    const uint4* __restrict__ ea_srt,
    const void* __restrict__ ew, const void* __restrict__ eb,
    const void* __restrict__ w1, const void* __restrict__ b1,
    const void* __restrict__ g,  const void* __restrict__ bb,
    const void* __restrict__ w2, const void* __restrict__ b2,
    const int* __restrict__ flg,
    u16* __restrict__ h_out)
{
    if (flg[0] != IS32) return;

    __shared__ u32 w1p[64*64];
    __shared__ u32 w2p[64*64];
    __shared__ u32 tbuf[4*2*256];

    int t = threadIdx.x;
    for (int i = t; i < 64*64; i += 256){
        int k = i >> 6, c = i & 63;
        u32 lo1, hi1, lo2, hi2;
        if (IS32){
            lo1 = f2bf(((const float*)w1)[k*128 + c]);
            hi1 = f2bf(((const float*)w1)[k*128 + c + 64]);
            lo2 = f2bf(((const float*)w2)[k*64 + c]);
            hi2 = f2bf(((const float*)w2)[(k+64)*64 + c]);
        } else {
            lo1 = ((const u16*)w1)[k*128 + c];
            hi1 = ((const u16*)w1)[k*128 + c + 64];
            lo2 = ((const u16*)w2)[k*64 + c];
            hi2 = ((const u16*)w2)[(k+64)*64 + c];
        }
        w1p[i] = lo1 | (hi1 << 16);
        w2p[i] = lo2 | (hi2 << 16);
    }
    __syncthreads();

    int lane = t & 63;
    int wslot = t >> 6;
    u32* tb0 = &tbuf[wslot*512];
    int wid  = (blockIdx.x*256 + t) >> 6;
    int nw   = (gridDim.x*256) >> 6;

    float ewr[16];
    #pragma unroll
    for (int k = 0; k < 16; k++) ewr[k] = ldx<IS32>(ew, k*64 + lane);
    float ebr = ldx<IS32>(eb, lane);
    const float BNS = 0.9999950000374997f;
    float b1a = ldx<IS32>(b1, lane), b1b = ldx<IS32>(b1, lane+64);
    float ga  = ldx<IS32>(g, lane)*BNS,  gb  = ldx<IS32>(g, lane+64)*BNS;
    float bba = ldx<IS32>(bb, lane),     bbb = ldx<IS32>(bb, lane+64);
    float b2r = ldx<IS32>(b2, lane);

    int elane = lane >> 3;
    int eq    = lane & 7;

    for (int node = wid; node < NN; node += nw){
        int p0 = row_ptr[node], p1 = row_ptr[node+1];
        if (p0 < 0) p0 = 0;
        if (p1 > NE) p1 = NE;
        u32 hw_ = ((const u32*)h_in)[(size_t)node*32 + (lane >> 1)];
        float hself = (lane & 1) ? bf_hi(hw_) : bf_lo(hw_);

        float m = -1e30f, sw = 0.f, swm = 0.f;

        for (int base = p0; base < p1; base += 64){
            int nch = p1 - base; if (nch > 64) nch = 64;
            int sidx = 0;
            if (lane < nch) sidx = pair_sorted[base + lane].x;

            int ngr = (nch + 7) >> 3;
            int slot0 = elane; if (slot0 >= nch) slot0 = nch - 1;
            int s_g   = __shfl(sidx, slot0, 64);
            uint4 hv  = ((const uint4*)h_in)[(size_t)s_g*8 + eq];

            for (int gidx = 0; gidx < ngr; ++gidx){
                uint4 hvn = hv;
                if (gidx + 1 < ngr){
                    int sl = (gidx+1)*8 + elane; if (sl >= nch) sl = nch - 1;
                    int sn = __shfl(sidx, sl, 64);
                    hvn = ((const uint4*)h_in)[(size_t)sn*8 + eq];
                }
                u32* lb = tb0 + ((gidx & 1) << 8);
                ((uint4*)lb)[lane] = hv;
                float hr[8];
                #pragma unroll
                for (int e = 0; e < 8; e++){
                    u32 w = lb[e*32 + (lane >> 1)];
                    hr[e] = (lane & 1) ? bf_hi(w) : bf_lo(w);
                }

                #pragma unroll
                for (int sub = 0; sub < 2; ++sub){
                    int sbase = gidx*8 + sub*4;
                    int nv = nch - sbase;
                    if (nv > 0){
                        if (nv > 4) nv = 4;
                        int l0 = sbase;
                        int l1 = l0 + (nv > 1);
                        int l2 = l1 + (nv > 2);
                        int l3 = l2 + (nv > 3);
                        uint4 A0 = ea_srt[(size_t)(base+l0)*2], B0 = ea_srt[(size_t)(base+l0)*2+1];
                        uint4 A1 = ea_srt[(size_t)(base+l1)*2], B1 = ea_srt[(size_t)(base+l1)*2+1];
                        uint4 A2 = ea_srt[(size_t)(base+l2)*2], B2 = ea_srt[(size_t)(base+l2)*2+1];
                        uint4 A3 = ea_srt[(size_t)(base+l3)*2], B3 = ea_srt[(size_t)(base+l3)*2+1];

                        float v0 = fmaxf(hr[sub*4+0] + edot(A0, B0, ewr, ebr), 0.f) + 1e-7f;
                        float v1 = fmaxf(hr[sub*4+1] + edot(A1, B1, ewr, ebr), 0.f) + 1e-7f;
                        float v2 = fmaxf(hr[sub*4+2] + edot(A2, B2, ewr, ebr), 0.f) + 1e-7f;
                        float v3 = fmaxf(hr[sub*4+3] + edot(A3, B3, ewr, ebr), 0.f) + 1e-7f;

                        float vm = v0;
                        if (nv > 1) vm = fmaxf(vm, v1);
                        if (nv > 2) vm = fmaxf(vm, v2);
                        if (nv > 3) vm = fmaxf(vm, v3);
                        float nm = fmaxf(m, vm);
                        float sc = __expf(m - nm);
                        sw *= sc; swm *= sc;
                        float pw;
                        pw = __expf(v0 - nm); sw += pw; swm += pw*v0;
                        if (nv > 1){ pw = __expf(v1 - nm); sw += pw; swm += pw*v1; }
                        if (nv > 2){ pw = __expf(v2 - nm); sw += pw; swm += pw*v2; }
                        if (nv > 3){ pw = __expf(v3 - nm); sw += pw; swm += pw*v3; }
                        m = nm;
                    }
                }
                hv = hvn;
            }
        }
        float agg = (sw > 0.f) ? (swm / sw) : 0.f;
        float out = agg + hself;

        float acc1 = b1a, acc2 = b1b;
        #pragma unroll
        for (int k = 0; k < 64; k++){
            float ok = __shfl(out, k, 64);
            u32 wp = w1p[k*64 + lane];
            acc1 = fmaf(ok, bf_lo(wp), acc1);
            acc2 = fmaf(ok, bf_hi(wp), acc2);
        }
        float hh1 = fmaxf(fmaf(acc1, ga, bba), 0.f);
        float hh2 = fmaxf(fmaf(acc2, gb, bbb), 0.f);
        float acc = b2r;
        #pragma unroll
        for (int j = 0; j < 64; j++){
            float a1 = __shfl(hh1, j, 64);
            float a2 = __shfl(hh2, j, 64);
            u32 wp = w2p[j*64 + lane];
            acc = fmaf(a1, bf_lo(wp), acc);
            acc = fmaf(a2, bf_hi(wp), acc);
        }
        float vfin = fmaxf(acc, 0.f);
        float vnext = __shfl_xor(vfin, 1, 64);
        if (!(lane & 1))
            ((u32*)h_out)[(size_t)node*32 + (lane >> 1)] = pack2(vfin, vnext);
    }
}

// ---------------- head: out = concat(h, gf) @ head_w + head_b  (FP32 OUT) ----------------
template<int IS32>
__global__ __launch_bounds__(256) void k_head(const u16* __restrict__ h,
                                              const void* __restrict__ gf,
                                              const int* __restrict__ ngp,
                                              const void* __restrict__ hw,
                                              const void* __restrict__ hb,
                                              const int* __restrict__ flg,
                                              float* __restrict__ out){
    if (flg[0] != IS32) return;
    int lane = threadIdx.x & 63;
    int wid  = (blockIdx.x*256 + threadIdx.x) >> 6;
    int nw   = (gridDim.x*256) >> 6;
    int dw = lane & 31;
    bool active = lane < 32;
    float wc0 = active ? ldx<IS32>(hw, 2*dw)     : 0.f;
    float wc1 = active ? ldx<IS32>(hw, 2*dw + 1) : 0.f;
    float w64 = ldx<IS32>(hw, 64), w65 = ldx<IS32>(hw, 65);
    float bias = ldx<IS32>(hb, 0);
    int ng  = ngp[0];
    if (ng <= 0) ng = 1;
    int npg = NN / ng;
    if (npg <= 0) npg = 1;
    for (int node = wid; node < NN; node += nw){
        float v = 0.f;
        if (active){
            u32 w = ((const u32*)h)[(size_t)node*32 + dw];
            v = bf_lo(w)*wc0 + bf_hi(w)*wc1;
        }
        #pragma unroll
        for (int off = 32; off > 0; off >>= 1) v += __shfl_xor(v, off, 64);
        if (lane == 0){
            int gidx = node / npg, r = node - gidx*npg;
            float g0 = ldx<IS32>(gf, (gidx*2 + 0)*npg + r);
            float g1 = ldx<IS32>(gf, (gidx*2 + 1)*npg + r);
            out[node] = v + g0*w64 + g1*w65 + bias;
        }
    }
}

// ---------------- launch ----------------
extern "C" void kernel_launch(void* const* d_in, const int* in_sizes, int n_in,
                              void* d_out, int out_size, void* d_ws, size_t ws_size,
                              hipStream_t stream){
    const void* x    = d_in[0];
    const int*  ei   = (const int*)d_in[1];          // [2, NE]: row0=src, row1=dst
    const void* ea   = d_in[2];
    const int*  ngp  = (const int*)d_in[3];
    const void* gf   = d_in[4];
    const void* srcw = d_in[5];
    const void* srcb = d_in[6];
    const void* L[16];
    for (int i = 0; i < 16; i++) L[i] = d_in[7 + i];
    const void* headw = d_in[23];
    const void* headb = d_in[24];

    char* ws = (char*)d_ws;
    size_t off = 0;
    auto alloc = [&](size_t bytes) -> void* {
        void* p = ws + off;
        off += (bytes + 255) & ~size_t(255);
        return p;
    };
    u16* hA          = (u16*)  alloc((size_t)NN*64*2);    // 12.8 MB
    u16* hB          = (u16*)  alloc((size_t)NN*64*2);    // 12.8 MB
    int* row_ptr     = (int*)  alloc((size_t)(NN+1)*4);
    int* cnt         = (int*)  alloc((size_t)2*NN*4);     // deg | fill
    int* deg  = cnt;
    int* fill = cnt + NN;
    int* csum        = (int*)  alloc((size_t)NCHUNK*4);
    int* coff        = (int*)  alloc((size_t)NCHUNK*4);
    int* flg         = (int*)  alloc(256);
    int2* pair_sorted= (int2*) alloc((size_t)NE*8);       // 12.8 MB
    uint4* ea_srt    = (uint4*)alloc((size_t)NE*32);      // 51.2 MB
    // adaptive msg chunking: fp16 msg = 128 B per edge (64 ch x 2B)
    size_t avail = (ws_size > off) ? (ws_size - off) : 0;
    int nch = 0; long cap = 0;
    {
        const int cands[6] = {1, 2, 4, 8, 16, 32};
        for (int ci = 0; ci < 6; ci++){
            int c = cands[ci];
            long need = (c == 1) ? (long)NE
                                 : (long)((double)NE / c * 1.2) + 4096;
            need = (need + 7) & ~7L;                      // multiple of 8
            if ((size_t)need * 128 + (1u<<20) <= avail){ nch = c; cap = need; break; }
        }
    }
    uint4* msgbuf = nch ? (uint4*)alloc((size_t)cap * 128) : nullptr;

    hipMemsetAsync(cnt, 0, (size_t)2*NN*4, stream);

    const int* e_src = ei;
    const int* e_dst = ei + NE;

    k_sniff      <<<1, 256, 0, stream>>>((const u32*)x, flg);
    k_deg        <<<1024, 256, 0, stream>>>(e_dst, deg);
    k_csum       <<<NCHUNK, 256, 0, stream>>>(deg, csum);
    k_scan_chunks<<<1, 512, 0, stream>>>(csum, coff);
    k_rowptr     <<<NCHUNK, 256, 0, stream>>>(deg, coff, row_ptr);
    k_scatter    <<<1024, 256, 0, stream>>>(e_src, e_dst, row_ptr, fill, pair_sorted);

    k_reorder<1> <<<2048, 256, 0, stream>>>(pair_sorted, ea, flg, ea_srt);
    k_reorder<0> <<<2048, 256, 0, stream>>>(pair_sorted, ea, flg, ea_srt);

    k_proj<1>    <<<512, 256, 0, stream>>>(x, srcw, srcb, flg, hA);
    k_proj<0>    <<<512, 256, 0, stream>>>(x, srcw, srcb, flg, hA);

    if (nch){
        int nc = (NN + nch - 1) / nch;
        for (int layer = 0; layer < 2; layer++){
            const u16* hin  = layer ? hB : hA;
            u16*       hout = layer ? hA : hB;
            const void* ewp = L[layer*8 + 0], *ebp = L[layer*8 + 1];
            const void* w1p = L[layer*8 + 2], *b1p = L[layer*8 + 3];
            const void* gp  = L[layer*8 + 4], *bbp = L[layer*8 + 5];
            const void* w2p = L[layer*8 + 6], *b2p = L[layer*8 + 7];
            for (int c = 0; c < nch; c++){
                int n0 = c * nc;
                int n1 = n0 + nc; if (n1 > NN) n1 = NN;
                if (n0 >= n1) break;
                k_msg<1> <<<2048, 256, 0, stream>>>(hin, row_ptr, pair_sorted, ea_srt,
                                ewp, ebp, flg, msgbuf, n0, n1, (int)cap);
                k_msg<0> <<<2048, 256, 0, stream>>>(hin, row_ptr, pair_sorted, ea_srt,
                                ewp, ebp, flg, msgbuf, n0, n1, (int)cap);
                k_sm<1>  <<<1024, 256, 0, stream>>>(hin, row_ptr, msgbuf,
                                w1p, b1p, gp, bbp, w2p, b2p, flg, hout, n0, n1, (int)cap);
                k_sm<0>  <<<1024, 256, 0, stream>>>(hin, row_ptr, msgbuf,
                                w1p, b1p, gp, bbp, w2p, b2p, flg, hout, n0, n1, (int)cap);
            }
        }
    } else {
        k_layer<1> <<<1024, 256, 0, stream>>>(hA, row_ptr, pair_sorted, ea_srt,
                        L[0], L[1], L[2], L[3], L[4], L[5], L[6], L[7], flg, hB);
        k_layer<0> <<<1024, 256, 0, stream>>>(hA, row_ptr, pair_sorted, ea_srt,
                        L[0], L[1], L[2], L[3], L[4], L[5], L[6], L[7], flg, hB);
        k_layer<1> <<<1024, 256, 0, stream>>>(hB, row_ptr, pair_sorted, ea_srt,
                        L[8], L[9], L[10], L[11], L[12], L[13], L[14], L[15], flg, hA);
        k_layer<0> <<<1024, 256, 0, stream>>>(hB, row_ptr, pair_sorted, ea_srt,
                        L[8], L[9], L[10], L[11], L[12], L[13], L[14], L[15], flg, hA);
    }

    k_head<1>    <<<512, 256, 0, stream>>>(hA, gf, ngp, headw, headb, flg, (float*)d_out);
    k_head<0>    <<<512, 256, 0, stream>>>(hA, gf, ngp, headw, headb, flg, (float*)d_out);
}

// Round 8
// 2051.280 us; speedup vs baseline: 3.9828x; 1.3695x over previous
//
#include <hip/hip_runtime.h>
#include <hip/hip_bf16.h>

#define NN 100000
#define NE 1600000
#define NCHUNK 391   // ceil(100000/256)

typedef unsigned short u16;
typedef unsigned int   u32;

__device__ __forceinline__ float bfu(u32 v){ union{u32 i; float f;} w; w.i = v<<16; return w.f; }
__device__ __forceinline__ float bf_lo(u32 u){ return bfu(u & 0xffffu); }
__device__ __forceinline__ float bf_hi(u32 u){ return bfu(u >> 16); }
__device__ __forceinline__ float bf16f(u16 u){ return bfu((u32)u); }
__device__ __forceinline__ u16 f2bf(float f){
    union{float f; u32 i;} w; w.f = f;
    u32 r = (w.i + 0x7fffu + ((w.i >> 16) & 1u)) >> 16;   // RNE
    return (u16)r;
}
__device__ __forceinline__ u32 pack2(float lo, float hi){
    return (u32)f2bf(lo) | ((u32)f2bf(hi) << 16);
}
// uniform-lane broadcast via v_readlane (SGPR result) — replaces ds_bpermute shfl
__device__ __forceinline__ float bcastf(float x, int l){
    return __int_as_float(__builtin_amdgcn_readlane(__float_as_int(x), l));
}
__device__ __forceinline__ int bcasti(int x, int l){
    return __builtin_amdgcn_readlane(x, l);
}

template<int IS32>
__device__ __forceinline__ float ldx(const void* p, int i){
    if (IS32) return ((const float*)p)[i];
    else      return bf16f(((const u16*)p)[i]);
}

// ---------------- dtype sniff: fp32 (1) vs bf16 (0) ----------------
__global__ void k_sniff(const u32* __restrict__ x, int* __restrict__ flag){
    __shared__ int cnt[256];
    int t = threadIdx.x;
    int bad = 0;
    for (int i = t; i < 512; i += 256){
        u32 w = x[i];
        u32 lo = w & 0xffffu;
        u32 e = (lo >> 7) & 0xffu;
        bool sane = (lo == 0u) || (lo == 0x8000u) || (e >= 85u && e <= 133u);
        if (!sane) bad++;
    }
    cnt[t] = bad; __syncthreads();
    for (int s = 128; s > 0; s >>= 1){
        if (t < s) cnt[t] += cnt[t+s];
        __syncthreads();
    }
    if (t == 0) flag[0] = (cnt[0] > 100) ? 1 : 0;
}

// ---------------- CSR build (dtype-independent) ----------------

__global__ void k_deg(const int* __restrict__ dst, int* __restrict__ deg){
    int stride = gridDim.x * blockDim.x;
    for (int i = blockIdx.x*blockDim.x + threadIdx.x; i < NE; i += stride){
        int d = dst[i];
        if ((unsigned)d < (unsigned)NN) atomicAdd(&deg[d], 1);
    }
}

__global__ void k_csum(const int* __restrict__ deg, int* __restrict__ csum){
    __shared__ int sdata[256];
    int t = threadIdx.x;
    int idx = blockIdx.x*256 + t;
    sdata[t] = (idx < NN) ? deg[idx] : 0;
    __syncthreads();
    for (int s = 128; s > 0; s >>= 1){
        if (t < s) sdata[t] += sdata[t+s];
        __syncthreads();
    }
    if (t == 0) csum[blockIdx.x] = sdata[0];
}

__global__ void k_scan_chunks(const int* __restrict__ csum, int* __restrict__ coff){
    __shared__ int s[512];
    int t = threadIdx.x;
    int v = (t < NCHUNK) ? csum[t] : 0;
    s[t] = v; __syncthreads();
    int x = v;
    for (int off = 1; off < 512; off <<= 1){
        int y = (t >= off) ? s[t-off] : 0;
        __syncthreads();
        x += y; s[t] = x;
        __syncthreads();
    }
    if (t < NCHUNK) coff[t] = x - v;   // exclusive
}

__global__ void k_rowptr(const int* __restrict__ deg, const int* __restrict__ coff,
                         int* __restrict__ row_ptr){
    __shared__ int s[256];
    int t = threadIdx.x, b = blockIdx.x;
    int idx = b*256 + t;
    int v = (idx < NN) ? deg[idx] : 0;
    s[t] = v; __syncthreads();
    int x = v;
    for (int off = 1; off < 256; off <<= 1){
        int y = (t >= off) ? s[t-off] : 0;
        __syncthreads();
        x += y; s[t] = x;
        __syncthreads();
    }
    if (idx < NN)       row_ptr[idx] = coff[b] + x - v;   // exclusive
    if (idx == NN - 1)  row_ptr[NN]  = coff[b] + x;       // total = NE
}

__global__ void k_scatter(const int* __restrict__ src, const int* __restrict__ dst,
                          const int* __restrict__ row_ptr, int* __restrict__ fill,
                          int2* __restrict__ pair_sorted){
    int stride = gridDim.x * blockDim.x;
    for (int i = blockIdx.x*blockDim.x + threadIdx.x; i < NE; i += stride){
        int d = dst[i];
        if ((unsigned)d >= (unsigned)NN) continue;
        int p = row_ptr[d] + atomicAdd(&fill[d], 1);
        if ((unsigned)p < (unsigned)NE){
            int s = src[i];
            if ((unsigned)s >= (unsigned)NN) s = 0;
            pair_sorted[p] = make_int2(s, i);
        }
    }
}

// ---------------- edge-attr reorder into p-sorted order (bf16 packed) ----------------
template<int IS32>
__global__ __launch_bounds__(256) void k_reorder(const int2* __restrict__ pair_sorted,
                                                 const void* __restrict__ ea,
                                                 const int* __restrict__ flg,
                                                 uint4* __restrict__ ea_srt){
    if (flg[0] != IS32) return;
    int stride = gridDim.x * blockDim.x;
    for (int p = blockIdx.x*blockDim.x + threadIdx.x; p < NE; p += stride){
        int eid = pair_sorted[p].y;
        if ((unsigned)eid >= (unsigned)NE) eid = 0;
        uint4 o0, o1;
        if (IS32){
            const float4* er = (const float4*)ea + (size_t)eid*4;
            float4 u0 = er[0], u1 = er[1], u2 = er[2], u3 = er[3];
            o0.x = pack2(u0.x, u0.y); o0.y = pack2(u0.z, u0.w);
            o0.z = pack2(u1.x, u1.y); o0.w = pack2(u1.z, u1.w);
            o1.x = pack2(u2.x, u2.y); o1.y = pack2(u2.z, u2.w);
            o1.z = pack2(u3.x, u3.y); o1.w = pack2(u3.z, u3.w);
        } else {
            const uint4* er = (const uint4*)ea + (size_t)eid*2;
            o0 = er[0]; o1 = er[1];
        }
        ea_srt[(size_t)p*2 + 0] = o0;
        ea_srt[(size_t)p*2 + 1] = o1;
    }
}

// ---------------- input projection ----------------
template<int IS32>
__global__ __launch_bounds__(256) void k_proj(const void* __restrict__ x,
                                              const void* __restrict__ w,
                                              const void* __restrict__ b,
                                              const int* __restrict__ flg,
                                              u16* __restrict__ h){
    if (flg[0] != IS32) return;
    int lane = threadIdx.x & 63;
    int wid  = (blockIdx.x*256 + threadIdx.x) >> 6;
    int nw   = (gridDim.x*256) >> 6;
    float wr[32];
    #pragma unroll
    for (int k = 0; k < 32; k++) wr[k] = ldx<IS32>(w, k*64 + lane);
    float bias = ldx<IS32>(b, lane);
    for (int node = wid; node < NN; node += nw){
        float acc = bias;
        if (IS32){
            const float* xr = (const float*)x + (size_t)node*32;
            #pragma unroll
            for (int k = 0; k < 32; k++) acc = fmaf(xr[k], wr[k], acc);
        } else {
            const u16* xr = (const u16*)x + (size_t)node*32;
            #pragma unroll
            for (int k = 0; k < 32; k++) acc = fmaf(bf16f(xr[k]), wr[k], acc);
        }
        float accn = __shfl_xor(acc, 1, 64);
        if (!(lane & 1))
            ((u32*)h)[(size_t)node*32 + (lane >> 1)] = pack2(acc, accn);
    }
}

// 16-channel dot of one bf16-packed edge-attr row with per-lane ew column
__device__ __forceinline__ float edot(uint4 a, uint4 b, const float* ewr, float ebr){
    float e = ebr;
    e = fmaf(bf_lo(a.x), ewr[0],  e); e = fmaf(bf_hi(a.x), ewr[1],  e);
    e = fmaf(bf_lo(a.y), ewr[2],  e); e = fmaf(bf_hi(a.y), ewr[3],  e);
    e = fmaf(bf_lo(a.z), ewr[4],  e); e = fmaf(bf_hi(a.z), ewr[5],  e);
    e = fmaf(bf_lo(a.w), ewr[6],  e); e = fmaf(bf_hi(a.w), ewr[7],  e);
    e = fmaf(bf_lo(b.x), ewr[8],  e); e = fmaf(bf_hi(b.x), ewr[9],  e);
    e = fmaf(bf_lo(b.y), ewr[10], e); e = fmaf(bf_hi(b.y), ewr[11], e);
    e = fmaf(bf_lo(b.z), ewr[12], e); e = fmaf(bf_hi(b.z), ewr[13], e);
    e = fmaf(bf_lo(b.w), ewr[14], e); e = fmaf(bf_hi(b.w), ewr[15], e);
    return e;
}

// ================= FULLY-FUSED LAYER (single pass, no msg buffer) =================
// Node-aligned contiguous wave ranges -> segmented softmax reduce entirely in
// registers (no atomics). Per 8-edge tile: 8 independent line-coalesced 128B
// h-row gathers (lane=channel, no transpose) + sequential 32B ea reads.
// exp(v - 16) constant shift: mathematically identical ratio swm/sw, no
// running-max serial chain (v = relu+eps bounded <<16+88, overflow-safe).
// MLP broadcasts via v_readlane (SGPR) instead of ds_bpermute shfl.
template<int IS32>
__global__ __launch_bounds__(256, 3) void k_fused(
    const u16*   __restrict__ h_in,
    const int*   __restrict__ row_ptr,
    const int2*  __restrict__ pair_sorted,
    const uint4* __restrict__ ea_srt,
    const void* __restrict__ ew, const void* __restrict__ eb,
    const void* __restrict__ w1, const void* __restrict__ b1,
    const void* __restrict__ g,  const void* __restrict__ bb,
    const void* __restrict__ w2, const void* __restrict__ b2,
    const int* __restrict__ flg,
    u16* __restrict__ h_out)
{
    if (flg[0] != IS32) return;

    __shared__ u32 w1p[64*64];       // 16 KB: lo=w1[k][c], hi=w1[k][c+64]
    __shared__ u32 w2p[64*64];       // 16 KB: lo=w2[k][c], hi=w2[k+64][c]
    __shared__ u16 sbuf[4][4*64];    // per-wave 512B output transpose scratch

    int t = threadIdx.x;
    for (int i = t; i < 64*64; i += 256){
        int k = i >> 6, c = i & 63;
        u32 lo1, hi1, lo2, hi2;
        if (IS32){
            lo1 = f2bf(((const float*)w1)[k*128 + c]);
            hi1 = f2bf(((const float*)w1)[k*128 + c + 64]);
            lo2 = f2bf(((const float*)w2)[k*64 + c]);
            hi2 = f2bf(((const float*)w2)[(k+64)*64 + c]);
        } else {
            lo1 = ((const u16*)w1)[k*128 + c];
            hi1 = ((const u16*)w1)[k*128 + c + 64];
            lo2 = ((const u16*)w2)[k*64 + c];
            hi2 = ((const u16*)w2)[(k+64)*64 + c];
        }
        w1p[i] = lo1 | (hi1 << 16);
        w2p[i] = lo2 | (hi2 << 16);
    }
    __syncthreads();

    int lane  = t & 63;
    int wslot = t >> 6;
    u16* sb   = sbuf[wslot];

    float ewr[16];
    #pragma unroll
    for (int k = 0; k < 16; k++) ewr[k] = ldx<IS32>(ew, k*64 + lane);
    float ebr = ldx<IS32>(eb, lane);
    const float BNS = 0.9999950000374997f;   // 1/sqrt(1+1e-5)
    float b1a = ldx<IS32>(b1, lane), b1b = ldx<IS32>(b1, lane+64);
    float ga  = ldx<IS32>(g, lane)*BNS,  gb  = ldx<IS32>(g, lane+64)*BNS;
    float bba = ldx<IS32>(bb, lane),     bbb = ldx<IS32>(bb, lane+64);
    float b2r = ldx<IS32>(b2, lane);

    // contiguous node sub-range for this wave
    int npb = (NN + gridDim.x - 1) / gridDim.x;
    int bn0 = blockIdx.x * npb;
    int bn1 = bn0 + npb; if (bn1 > NN) bn1 = NN;
    int wnpb = (npb + 3) >> 2;
    int wn0 = bn0 + wslot * wnpb;
    int wn1 = wn0 + wnpb; if (wn1 > bn1) wn1 = bn1;

    bool odd = (lane & 1);
    int hw_i = lane >> 1;

    for (int nb = wn0; nb < wn1; nb += 4){
        int cntn = wn1 - nb; if (cntn > 4) cntn = 4;
        float outv[4];

        for (int j = 0; j < 4; ++j){
            if (j >= cntn){ outv[j] = 0.f; continue; }
            int node = nb + j;
            int q0 = row_ptr[node], q1 = row_ptr[node+1];
            if (q0 < 0) q0 = 0;
            if (q1 > NE) q1 = NE;
            u32 hwv = ((const u32*)h_in)[(size_t)node*32 + hw_i];
            float hself = odd ? bf_hi(hwv) : bf_lo(hwv);

            float sw = 0.f, swm = 0.f;
            for (int qb = q0; qb < q1; qb += 8){
                int nv = q1 - qb; if (nv > 8) nv = 8;
                // 8 src ids via one cooperative 64B load, broadcast by readlane
                int sp = 0;
                if (lane < 8){
                    int q = qb + lane; if (q >= q1) q = q1 - 1;
                    sp = pair_sorted[q].x;
                    if ((unsigned)sp >= (unsigned)NN) sp = 0;
                }
                #pragma unroll
                for (int e = 0; e < 8; ++e){
                    if (e < nv){                       // wave-uniform predicate
                        int s = bcasti(sp, e);
                        u32 hr = ((const u32*)h_in)[(size_t)s*32 + hw_i];
                        uint4 A = ea_srt[(size_t)(qb+e)*2];
                        uint4 B = ea_srt[(size_t)(qb+e)*2 + 1];
                        float hs = odd ? bf_hi(hr) : bf_lo(hr);
                        float v = fmaxf(hs + edot(A, B, ewr, ebr), 0.f) + 1e-7f;
                        float p = __expf(v - 16.f);    // constant shift, exact in ratio
                        sw += p; swm += p * v;
                    }
                }
            }
            float agg = (sw > 0.f) ? (swm / sw) : 0.f;
            outv[j] = agg + hself;
        }

        // batched MLP: 4 nodes, readlane broadcasts (no LDS-pipe shfl)
        float acc1[4], acc2[4];
        #pragma unroll
        for (int j = 0; j < 4; j++){ acc1[j] = b1a; acc2[j] = b1b; }
        #pragma unroll
        for (int k = 0; k < 64; k++){
            u32 wp = w1p[k*64 + lane];
            float wl = bf_lo(wp), wh = bf_hi(wp);
            #pragma unroll
            for (int j = 0; j < 4; j++){
                float ok = bcastf(outv[j], k);
                acc1[j] = fmaf(ok, wl, acc1[j]);
                acc2[j] = fmaf(ok, wh, acc2[j]);
            }
        }
        float hh1[4], hh2[4], acc[4];
        #pragma unroll
        for (int j = 0; j < 4; j++){
            hh1[j] = fmaxf(fmaf(acc1[j], ga, bba), 0.f);
            hh2[j] = fmaxf(fmaf(acc2[j], gb, bbb), 0.f);
            acc[j] = b2r;
        }
        #pragma unroll
        for (int k = 0; k < 64; k++){
            u32 wp = w2p[k*64 + lane];
            float wl = bf_lo(wp), wh = bf_hi(wp);
            #pragma unroll
            for (int j = 0; j < 4; j++){
                float a1 = bcastf(hh1[j], k);
                float a2 = bcastf(hh2[j], k);
                acc[j] = fmaf(a1, wl, acc[j]);
                acc[j] = fmaf(a2, wh, acc[j]);
            }
        }

        if (cntn == 4){
            // dense full-wave store: LDS transpose 4x[64]u16 -> uint2/lane (512B)
            #pragma unroll
            for (int j = 0; j < 4; j++)
                sb[j*64 + lane] = f2bf(fmaxf(acc[j], 0.f));
            uint2 ov = ((const uint2*)sb)[lane];   // wave-private; lgkmcnt auto
            ((uint2*)(h_out + (size_t)nb*64))[lane] = ov;
        } else {
            for (int j = 0; j < cntn; j++){
                float vfin = fmaxf(acc[j], 0.f);
                float vnext = __shfl_xor(vfin, 1, 64);
                if (!(lane & 1))
                    ((u32*)h_out)[(size_t)(nb+j)*32 + (lane >> 1)] = pack2(vfin, vnext);
            }
        }
    }
}

// ---------------- head: out = concat(h, gf) @ head_w + head_b  (FP32 OUT) ----------------
template<int IS32>
__global__ __launch_bounds__(256) void k_head(const u16* __restrict__ h,
                                              const void* __restrict__ gf,
                                              const int* __restrict__ ngp,
                                              const void* __restrict__ hw,
                                              const void* __restrict__ hb,
                                              const int* __restrict__ flg,
                                              float* __restrict__ out){
    if (flg[0] != IS32) return;
    int lane = threadIdx.x & 63;
    int wid  = (blockIdx.x*256 + threadIdx.x) >> 6;
    int nw   = (gridDim.x*256) >> 6;
    int dw = lane & 31;
    bool active = lane < 32;
    float wc0 = active ? ldx<IS32>(hw, 2*dw)     : 0.f;
    float wc1 = active ? ldx<IS32>(hw, 2*dw + 1) : 0.f;
    float w64 = ldx<IS32>(hw, 64), w65 = ldx<IS32>(hw, 65);
    float bias = ldx<IS32>(hb, 0);
    int ng  = ngp[0];
    if (ng <= 0) ng = 1;
    int npg = NN / ng;
    if (npg <= 0) npg = 1;
    for (int node = wid; node < NN; node += nw){
        float v = 0.f;
        if (active){
            u32 w = ((const u32*)h)[(size_t)node*32 + dw];
            v = bf_lo(w)*wc0 + bf_hi(w)*wc1;
        }
        #pragma unroll
        for (int off = 32; off > 0; off >>= 1) v += __shfl_xor(v, off, 64);
        if (lane == 0){
            int gidx = node / npg, r = node - gidx*npg;
            float g0 = ldx<IS32>(gf, (gidx*2 + 0)*npg + r);
            float g1 = ldx<IS32>(gf, (gidx*2 + 1)*npg + r);
            out[node] = v + g0*w64 + g1*w65 + bias;
        }
    }
}

// ---------------- launch ----------------
extern "C" void kernel_launch(void* const* d_in, const int* in_sizes, int n_in,
                              void* d_out, int out_size, void* d_ws, size_t ws_size,
                              hipStream_t stream){
    const void* x    = d_in[0];
    const int*  ei   = (const int*)d_in[1];          // [2, NE]: row0=src, row1=dst
    const void* ea   = d_in[2];
    const int*  ngp  = (const int*)d_in[3];
    const void* gf   = d_in[4];
    const void* srcw = d_in[5];
    const void* srcb = d_in[6];
    const void* L[16];
    for (int i = 0; i < 16; i++) L[i] = d_in[7 + i];
    const void* headw = d_in[23];
    const void* headb = d_in[24];

    char* ws = (char*)d_ws;
    size_t off = 0;
    auto alloc = [&](size_t bytes) -> void* {
        void* p = ws + off;
        off += (bytes + 255) & ~size_t(255);
        return p;
    };
    u16* hA          = (u16*)  alloc((size_t)NN*64*2);    // 12.8 MB
    u16* hB          = (u16*)  alloc((size_t)NN*64*2);    // 12.8 MB
    int* row_ptr     = (int*)  alloc((size_t)(NN+1)*4);
    int* cnt         = (int*)  alloc((size_t)2*NN*4);     // deg | fill
    int* deg  = cnt;
    int* fill = cnt + NN;
    int* csum        = (int*)  alloc((size_t)NCHUNK*4);
    int* coff        = (int*)  alloc((size_t)NCHUNK*4);
    int* flg         = (int*)  alloc(256);
    int2* pair_sorted= (int2*) alloc((size_t)NE*8);       // 12.8 MB
    uint4* ea_srt    = (uint4*)alloc((size_t)NE*32);      // 51.2 MB
    // total ~= 91 MB — no msg buffer needed any more

    hipMemsetAsync(cnt, 0, (size_t)2*NN*4, stream);

    const int* e_src = ei;
    const int* e_dst = ei + NE;

    k_sniff      <<<1, 256, 0, stream>>>((const u32*)x, flg);
    k_deg        <<<1024, 256, 0, stream>>>(e_dst, deg);
    k_csum       <<<NCHUNK, 256, 0, stream>>>(deg, csum);
    k_scan_chunks<<<1, 512, 0, stream>>>(csum, coff);
    k_rowptr     <<<NCHUNK, 256, 0, stream>>>(deg, coff, row_ptr);
    k_scatter    <<<1024, 256, 0, stream>>>(e_src, e_dst, row_ptr, fill, pair_sorted);

    k_reorder<1> <<<2048, 256, 0, stream>>>(pair_sorted, ea, flg, ea_srt);
    k_reorder<0> <<<2048, 256, 0, stream>>>(pair_sorted, ea, flg, ea_srt);

    k_proj<1>    <<<512, 256, 0, stream>>>(x, srcw, srcb, flg, hA);
    k_proj<0>    <<<512, 256, 0, stream>>>(x, srcw, srcb, flg, hA);

    // layer 0: hA -> hB
    k_fused<1>   <<<768, 256, 0, stream>>>(hA, row_ptr, pair_sorted, ea_srt,
                    L[0], L[1], L[2], L[3], L[4], L[5], L[6], L[7], flg, hB);
    k_fused<0>   <<<768, 256, 0, stream>>>(hA, row_ptr, pair_sorted, ea_srt,
                    L[0], L[1], L[2], L[3], L[4], L[5], L[6], L[7], flg, hB);
    // layer 1: hB -> hA
    k_fused<1>   <<<768, 256, 0, stream>>>(hB, row_ptr, pair_sorted, ea_srt,
                    L[8], L[9], L[10], L[11], L[12], L[13], L[14], L[15], flg, hA);
    k_fused<0>   <<<768, 256, 0, stream>>>(hB, row_ptr, pair_sorted, ea_srt,
                    L[8], L[9], L[10], L[11], L[12], L[13], L[14], L[15], flg, hA);

    k_head<1>    <<<512, 256, 0, stream>>>(hA, gf, ngp, headw, headb, flg, (float*)d_out);
    k_head<0>    <<<512, 256, 0, stream>>>(hA, gf, ngp, headw, headb, flg, (float*)d_out);
}